// Round 1
// baseline (285.164 us; speedup 1.0000x reference)
//
#include <hip/hip_runtime.h>

#define BATCH 4
#define SEQ 4096
#define DMODEL 1024
#define HDIM 64

typedef _Float16 h16;
typedef _Float16 h16x8 __attribute__((ext_vector_type(8)));
typedef float f32x4 __attribute__((ext_vector_type(4)));

#define WT_ELEMS (192 * DMODEL)
#define QK_ELEMS (BATCH * SEQ * HDIM)

// ---------------- W transpose + fp16 convert: Wt[n][k] = W_sel[k][n%64] ----------------
__global__ __launch_bounds__(256) void prep_w(const float* __restrict__ Wq,
                                              const float* __restrict__ Wk,
                                              const float* __restrict__ Wv,
                                              h16* __restrict__ Wt) {
    int n = blockIdx.x;  // 0..191
    const float* W = (n < 64) ? Wq : (n < 128) ? Wk : Wv;
    int c = n & 63;
    for (int k = threadIdx.x; k < DMODEL; k += 256)
        Wt[n * DMODEL + k] = (h16)W[k * HDIM + c];
}

// ---------------- QKV projection GEMM: M=16384, K=1024, N=192 ----------------
// grid 256 (64-row M tiles), 4 waves: wave w -> 48 N-cols (3 frags). MFMA 16x16x32 f16.
__global__ __launch_bounds__(256) void qkv_proj(
    const float* __restrict__ x, const h16* __restrict__ Wt,
    const float* __restrict__ bq, const float* __restrict__ bk, const float* __restrict__ bv,
    h16* __restrict__ Q, h16* __restrict__ K, h16* __restrict__ Vt)
{
    int lane = threadIdx.x & 63;
    int w = threadIdx.x >> 6;
    int r0 = blockIdx.x * 64;
    int ln15 = lane & 15;
    int kc = (lane >> 4) * 8;

    f32x4 acc[4][3];
    #pragma unroll
    for (int m = 0; m < 4; m++)
        #pragma unroll
        for (int f = 0; f < 3; f++) acc[m][f] = 0.f;

    for (int k0 = 0; k0 < DMODEL; k0 += 32) {
        h16x8 a[4], b[3];
        #pragma unroll
        for (int m = 0; m < 4; m++) {
            const float* xp = x + (size_t)(r0 + 16 * m + ln15) * DMODEL + k0 + kc;
            f32x4 lo = *(const f32x4*)xp;
            f32x4 hi = *(const f32x4*)(xp + 4);
            h16x8 av;
            #pragma unroll
            for (int j = 0; j < 4; j++) { av[j] = (h16)lo[j]; av[j + 4] = (h16)hi[j]; }
            a[m] = av;
        }
        #pragma unroll
        for (int f = 0; f < 3; f++) {
            int col = 48 * w + 16 * f + ln15;
            b[f] = *(const h16x8*)(Wt + (size_t)col * DMODEL + k0 + kc);
        }
        #pragma unroll
        for (int m = 0; m < 4; m++)
            #pragma unroll
            for (int f = 0; f < 3; f++)
                acc[m][f] = __builtin_amdgcn_mfma_f32_16x16x32_f16(a[m], b[f], acc[m][f], 0, 0, 0);
    }

    // epilogue: +bias, write Q,K row-major fp16; V transposed [B][H][T]
    #pragma unroll
    for (int f = 0; f < 3; f++) {
        int col = 48 * w + 16 * f + ln15;
        float bias = (col < 64) ? bq[col] : (col < 128) ? bk[col - 64] : bv[col - 128];
        #pragma unroll
        for (int m = 0; m < 4; m++) {
            #pragma unroll
            for (int i = 0; i < 4; i++) {
                int t = r0 + 16 * m + (lane >> 4) * 4 + i;
                int bb = t >> 12;
                int tt = t & (SEQ - 1);
                float v = acc[m][f][i] + bias;
                if (col < 64)
                    Q[((size_t)bb * SEQ + tt) * HDIM + col] = (h16)v;
                else if (col < 128)
                    K[((size_t)bb * SEQ + tt) * HDIM + (col - 64)] = (h16)v;
                else
                    Vt[((size_t)bb * HDIM + (col - 128)) * SEQ + tt] = (h16)v;
            }
        }
    }
}

// ---------------- causal flash attention: 1 wave per 16 q-rows, KVBLK=64 ----------------
__global__ __launch_bounds__(64) void flash(
    const h16* __restrict__ Q, const h16* __restrict__ K, const h16* __restrict__ Vt,
    float* __restrict__ out)
{
    __shared__ unsigned short plds[16 * 64];  // 2KB, XOR-swizzled P tile
    int lane = threadIdx.x;
    int bid = blockIdx.x;
    int batch = bid & 3;
    int qt = 255 - (bid >> 2);  // longest tiles dispatched first
    int q0 = qt * 16;
    int ln15 = lane & 15;
    int kc = (lane >> 4) * 8;

    const h16* Qb = Q + (size_t)batch * SEQ * HDIM;
    const h16* Kb = K + (size_t)batch * SEQ * HDIM;
    const h16* Vb = Vt + (size_t)batch * HDIM * SEQ;

    h16x8 qa[2];
    #pragma unroll
    for (int c = 0; c < 2; c++)
        qa[c] = *(const h16x8*)(Qb + (size_t)(q0 + ln15) * HDIM + 32 * c + kc);

    float m_i[4], l_i[4];
    f32x4 o[4];
    #pragma unroll
    for (int i = 0; i < 4; i++) { m_i[i] = -1e30f; l_i[i] = 0.f; }
    #pragma unroll
    for (int f = 0; f < 4; f++) o[f] = 0.f;

    int nt = (qt >> 2) + 1;
    for (int t = 0; t < nt; t++) {
        int kt0 = t * 64;
        f32x4 sc[4];
        #pragma unroll
        for (int f = 0; f < 4; f++) sc[f] = 0.f;
        #pragma unroll
        for (int c = 0; c < 2; c++)
            #pragma unroll
            for (int f = 0; f < 4; f++) {
                h16x8 kb = *(const h16x8*)(Kb + (size_t)(kt0 + 16 * f + ln15) * HDIM + 32 * c + kc);
                sc[f] = __builtin_amdgcn_mfma_f32_16x16x32_f16(qa[c], kb, sc[f], 0, 0, 0);
            }

        // scale + causal mask (only diagonal tile needs it)
        bool diag = (t == nt - 1);
        #pragma unroll
        for (int f = 0; f < 4; f++)
            #pragma unroll
            for (int i = 0; i < 4; i++) {
                float s = sc[f][i] * 0.125f;
                if (diag) {
                    int ktg = kt0 + 16 * f + ln15;
                    int qg = q0 + (lane >> 4) * 4 + i;
                    if (ktg > qg) s = -1e30f;
                }
                sc[f][i] = s;
            }

        // row max across the 16-lane col group
        float tm[4];
        #pragma unroll
        for (int i = 0; i < 4; i++)
            tm[i] = fmaxf(fmaxf(sc[0][i], sc[1][i]), fmaxf(sc[2][i], sc[3][i]));
        #pragma unroll
        for (int d = 1; d < 16; d <<= 1)
            #pragma unroll
            for (int i = 0; i < 4; i++) tm[i] = fmaxf(tm[i], __shfl_xor(tm[i], d));

        float al[4], rs[4];
        #pragma unroll
        for (int i = 0; i < 4; i++) {
            float mn = fmaxf(m_i[i], tm[i]);
            al[i] = __expf(m_i[i] - mn);
            m_i[i] = mn;
            rs[i] = 0.f;
        }

        // P = exp(s - m), row sums, store P to swizzled LDS as fp16
        #pragma unroll
        for (int f = 0; f < 4; f++)
            #pragma unroll
            for (int i = 0; i < 4; i++) {
                float p = __expf(sc[f][i] - m_i[i]);
                rs[i] += p;
                int row = (lane >> 4) * 4 + i;
                int byteoff = (row * 128 + (16 * f + ln15) * 2) ^ ((row & 7) << 4);
                *(h16*)((char*)plds + byteoff) = (h16)p;
            }
        #pragma unroll
        for (int d = 1; d < 16; d <<= 1)
            #pragma unroll
            for (int i = 0; i < 4; i++) rs[i] += __shfl_xor(rs[i], d);
        #pragma unroll
        for (int i = 0; i < 4; i++) l_i[i] = l_i[i] * al[i] + rs[i];
        #pragma unroll
        for (int f = 0; f < 4; f++)
            #pragma unroll
            for (int i = 0; i < 4; i++) o[f][i] *= al[i];

        asm volatile("s_waitcnt lgkmcnt(0)" ::: "memory");

        // PV: A = P (transposed via LDS), B = V via Vt (contiguous in t)
        #pragma unroll
        for (int c = 0; c < 2; c++) {
            int rb = (ln15 * 128 + (32 * c + kc) * 2) ^ ((ln15 & 7) << 4);
            h16x8 pa = *(const h16x8*)((char*)plds + rb);
            #pragma unroll
            for (int f = 0; f < 4; f++) {
                h16x8 vb = *(const h16x8*)(Vb + (size_t)(16 * f + ln15) * SEQ + kt0 + 32 * c + kc);
                o[f] = __builtin_amdgcn_mfma_f32_16x16x32_f16(pa, vb, o[f], 0, 0, 0);
            }
        }
    }

    #pragma unroll
    for (int f = 0; f < 4; f++)
        #pragma unroll
        for (int i = 0; i < 4; i++) {
            int qg = q0 + (lane >> 4) * 4 + i;
            out[((size_t)batch * SEQ + qg) * HDIM + 16 * f + ln15] = o[f][i] / l_i[i];
        }
}

extern "C" void kernel_launch(void* const* d_in, const int* in_sizes, int n_in,
                              void* d_out, int out_size, void* d_ws, size_t ws_size,
                              hipStream_t stream) {
    const float* x  = (const float*)d_in[0];
    const float* Wq = (const float*)d_in[1];
    const float* bq = (const float*)d_in[2];
    const float* Wk = (const float*)d_in[3];
    const float* bk = (const float*)d_in[4];
    const float* Wv = (const float*)d_in[5];
    const float* bv = (const float*)d_in[6];
    float* out = (float*)d_out;

    h16* Wt = (h16*)d_ws;
    h16* Q  = Wt + WT_ELEMS;
    h16* K  = Q + QK_ELEMS;
    h16* Vt = K + QK_ELEMS;

    hipLaunchKernelGGL(prep_w, dim3(192), dim3(256), 0, stream, Wq, Wk, Wv, Wt);
    hipLaunchKernelGGL(qkv_proj, dim3(256), dim3(256), 0, stream,
                       x, Wt, bq, bk, bv, Q, K, Vt);
    hipLaunchKernelGGL(flash, dim3(1024), dim3(64), 0, stream, Q, K, Vt, out);
}

// Round 2
// 223.630 us; speedup vs baseline: 1.2752x; 1.2752x over previous
//
#include <hip/hip_runtime.h>

#define BATCH 4
#define SEQ 4096
#define DMODEL 1024
#define HDIM 64
#define NQT 256      // q-tiles of 16 rows per batch
#define CHUNK 512    // KV positions per partial block
#define MAXC 8       // max chunks per q-tile (SEQ/CHUNK)

typedef _Float16 h16;
typedef _Float16 h16x8 __attribute__((ext_vector_type(8)));
typedef float f32x4 __attribute__((ext_vector_type(4)));

#define WT_ELEMS (192 * DMODEL)
#define QK_ELEMS (BATCH * SEQ * HDIM)
#define NSLOT (BATCH * NQT * MAXC)

// ---------------- W transpose + fp16 convert: Wt[n][k] = W_sel[k][n%64] ----------------
__global__ __launch_bounds__(256) void prep_w(const float* __restrict__ Wq,
                                              const float* __restrict__ Wk,
                                              const float* __restrict__ Wv,
                                              h16* __restrict__ Wt) {
    int n = blockIdx.x;  // 0..191
    const float* W = (n < 64) ? Wq : (n < 128) ? Wk : Wv;
    int c = n & 63;
    for (int k = threadIdx.x; k < DMODEL; k += 256)
        Wt[n * DMODEL + k] = (h16)W[k * HDIM + c];
}

// ---------------- QKV projection GEMM: M=16384, K=1024, N=192 ----------------
// grid 1024 (16-row tiles); 4 waves: wave w -> 48 N-cols (3 frags). MFMA 16x16x32 f16.
__global__ __launch_bounds__(256) void qkv_proj(
    const float* __restrict__ x, const h16* __restrict__ Wt,
    const float* __restrict__ bq, const float* __restrict__ bk, const float* __restrict__ bv,
    h16* __restrict__ Q, h16* __restrict__ K, h16* __restrict__ Vt)
{
    int lane = threadIdx.x & 63;
    int w = threadIdx.x >> 6;
    int r0 = blockIdx.x * 16;
    int ln15 = lane & 15;
    int kc = (lane >> 4) * 8;

    f32x4 acc[3];
    #pragma unroll
    for (int f = 0; f < 3; f++) acc[f] = 0.f;

    for (int k0 = 0; k0 < DMODEL; k0 += 32) {
        const float* xp = x + (size_t)(r0 + ln15) * DMODEL + k0 + kc;
        f32x4 lo = *(const f32x4*)xp;
        f32x4 hi = *(const f32x4*)(xp + 4);
        h16x8 av;
        #pragma unroll
        for (int j = 0; j < 4; j++) { av[j] = (h16)lo[j]; av[j + 4] = (h16)hi[j]; }
        h16x8 b[3];
        #pragma unroll
        for (int f = 0; f < 3; f++) {
            int col = 48 * w + 16 * f + ln15;
            b[f] = *(const h16x8*)(Wt + (size_t)col * DMODEL + k0 + kc);
        }
        #pragma unroll
        for (int f = 0; f < 3; f++)
            acc[f] = __builtin_amdgcn_mfma_f32_16x16x32_f16(av, b[f], acc[f], 0, 0, 0);
    }

    // epilogue: +bias, write Q,K row-major fp16; V transposed [B][H][T]
    #pragma unroll
    for (int f = 0; f < 3; f++) {
        int col = 48 * w + 16 * f + ln15;
        float bias = (col < 64) ? bq[col] : (col < 128) ? bk[col - 64] : bv[col - 128];
        #pragma unroll
        for (int i = 0; i < 4; i++) {
            int t = r0 + (lane >> 4) * 4 + i;
            int bb = t >> 12;
            int tt = t & (SEQ - 1);
            float v = acc[f][i] + bias;
            if (col < 64)
                Q[((size_t)bb * SEQ + tt) * HDIM + col] = (h16)v;
            else if (col < 128)
                K[((size_t)bb * SEQ + tt) * HDIM + (col - 64)] = (h16)v;
            else
                Vt[((size_t)bb * HDIM + (col - 128)) * SEQ + tt] = (h16)v;
        }
    }
}

// ---------------- causal flash attention partial: 1 wave per (batch, 16 q-rows, 512 kv) ----------------
__global__ __launch_bounds__(64) void flash(
    const h16* __restrict__ Q, const h16* __restrict__ K, const h16* __restrict__ Vt,
    float* __restrict__ o_part, float* __restrict__ ml_part)
{
    int bid = blockIdx.x;
    int c = bid & (MAXC - 1);
    int rest = bid >> 3;
    int qt = NQT - 1 - (rest & (NQT - 1));  // longest q-tiles dispatched first
    int batch = rest >> 8;
    int q0 = qt * 16;
    int nc = ((q0 + 15) >> 9) + 1;          // valid chunks for this q-tile
    if (c >= nc) return;

    __shared__ unsigned short plds[16 * 64];  // 2KB, XOR-swizzled P tile
    int lane = threadIdx.x;
    int ln15 = lane & 15;
    int kc = (lane >> 4) * 8;
    int S = c * CHUNK;

    const h16* Qb = Q + (size_t)batch * SEQ * HDIM;
    const h16* Kb = K + (size_t)batch * SEQ * HDIM;
    const h16* Vb = Vt + (size_t)batch * HDIM * SEQ;

    h16x8 qa[2];
    #pragma unroll
    for (int cc = 0; cc < 2; cc++)
        qa[cc] = *(const h16x8*)(Qb + (size_t)(q0 + ln15) * HDIM + 32 * cc + kc);

    float m_i[4], l_i[4];
    f32x4 o[4];
    #pragma unroll
    for (int i = 0; i < 4; i++) { m_i[i] = -1e30f; l_i[i] = 0.f; }
    #pragma unroll
    for (int f = 0; f < 4; f++) o[f] = 0.f;

    int gdiag = (q0 + 15) >> 6;                                 // global diagonal tile
    int lt = (c == nc - 1) ? (gdiag - (S >> 6) + 1) : (CHUNK / 64);
    for (int t = 0; t < lt; t++) {
        int kt0 = S + t * 64;
        f32x4 sc[4];
        #pragma unroll
        for (int f = 0; f < 4; f++) sc[f] = 0.f;
        #pragma unroll
        for (int cc = 0; cc < 2; cc++)
            #pragma unroll
            for (int f = 0; f < 4; f++) {
                h16x8 kb = *(const h16x8*)(Kb + (size_t)(kt0 + 16 * f + ln15) * HDIM + 32 * cc + kc);
                sc[f] = __builtin_amdgcn_mfma_f32_16x16x32_f16(qa[cc], kb, sc[f], 0, 0, 0);
            }

        // scale + causal mask (only the global diagonal tile needs it)
        bool diag = ((S >> 6) + t) == gdiag;
        #pragma unroll
        for (int f = 0; f < 4; f++)
            #pragma unroll
            for (int i = 0; i < 4; i++) {
                float s = sc[f][i] * 0.125f;
                if (diag) {
                    int ktg = kt0 + 16 * f + ln15;
                    int qg = q0 + (lane >> 4) * 4 + i;
                    if (ktg > qg) s = -1e30f;
                }
                sc[f][i] = s;
            }

        // row max across the 16-lane col group
        float tm[4];
        #pragma unroll
        for (int i = 0; i < 4; i++)
            tm[i] = fmaxf(fmaxf(sc[0][i], sc[1][i]), fmaxf(sc[2][i], sc[3][i]));
        #pragma unroll
        for (int d = 1; d < 16; d <<= 1)
            #pragma unroll
            for (int i = 0; i < 4; i++) tm[i] = fmaxf(tm[i], __shfl_xor(tm[i], d));

        float al[4], rs[4];
        #pragma unroll
        for (int i = 0; i < 4; i++) {
            float mn = fmaxf(m_i[i], tm[i]);
            al[i] = __expf(m_i[i] - mn);
            m_i[i] = mn;
            rs[i] = 0.f;
        }

        // P = exp(s - m), row sums, store P to swizzled LDS as fp16
        #pragma unroll
        for (int f = 0; f < 4; f++)
            #pragma unroll
            for (int i = 0; i < 4; i++) {
                float p = __expf(sc[f][i] - m_i[i]);
                rs[i] += p;
                int row = (lane >> 4) * 4 + i;
                int byteoff = (row * 128 + (16 * f + ln15) * 2) ^ ((row & 7) << 4);
                *(h16*)((char*)plds + byteoff) = (h16)p;
            }
        #pragma unroll
        for (int d = 1; d < 16; d <<= 1)
            #pragma unroll
            for (int i = 0; i < 4; i++) rs[i] += __shfl_xor(rs[i], d);
        #pragma unroll
        for (int i = 0; i < 4; i++) l_i[i] = l_i[i] * al[i] + rs[i];
        #pragma unroll
        for (int f = 0; f < 4; f++)
            #pragma unroll
            for (int i = 0; i < 4; i++) o[f][i] *= al[i];

        asm volatile("s_waitcnt lgkmcnt(0)" ::: "memory");

        // PV: A = P (transposed via LDS), B = V via Vt (contiguous in t)
        #pragma unroll
        for (int cc = 0; cc < 2; cc++) {
            int rb = (ln15 * 128 + (32 * cc + kc) * 2) ^ ((ln15 & 7) << 4);
            h16x8 pa = *(const h16x8*)((char*)plds + rb);
            #pragma unroll
            for (int f = 0; f < 4; f++) {
                h16x8 vb = *(const h16x8*)(Vb + (size_t)(16 * f + ln15) * SEQ + kt0 + 32 * cc + kc);
                o[f] = __builtin_amdgcn_mfma_f32_16x16x32_f16(pa, vb, o[f], 0, 0, 0);
            }
        }
    }

    // write partial (unnormalized o, running m, l) for this chunk
    size_t slot = ((size_t)batch * NQT + qt) * MAXC + c;
    float* op = o_part + slot * (16 * 64);
    #pragma unroll
    for (int f = 0; f < 4; f++)
        #pragma unroll
        for (int i = 0; i < 4; i++) {
            int row = (lane >> 4) * 4 + i;
            op[row * 64 + 16 * f + ln15] = o[f][i];
        }
    if (ln15 == 0) {
        #pragma unroll
        for (int i = 0; i < 4; i++) {
            int row = (lane >> 4) * 4 + i;
            ml_part[slot * 32 + row * 2] = m_i[i];
            ml_part[slot * 32 + row * 2 + 1] = l_i[i];
        }
    }
}

// ---------------- combine partials: one block per (batch, q-tile) ----------------
__global__ __launch_bounds__(256) void combine(
    const float* __restrict__ o_part, const float* __restrict__ ml_part,
    float* __restrict__ out)
{
    int bid = blockIdx.x;           // batch*NQT + qt
    int batch = bid >> 8;
    int qt = bid & (NQT - 1);
    int q0 = qt * 16;
    int nc = ((q0 + 15) >> 9) + 1;
    int col = threadIdx.x & 63;
    int rg = threadIdx.x >> 6;      // 0..3
    size_t base = (size_t)bid * MAXC;

    #pragma unroll
    for (int j = 0; j < 4; j++) {
        int r = rg * 4 + j;
        float M = -1e30f;
        for (int c = 0; c < nc; c++)
            M = fmaxf(M, ml_part[(base + c) * 32 + r * 2]);
        float L = 0.f, acc = 0.f;
        for (int c = 0; c < nc; c++) {
            float mc = ml_part[(base + c) * 32 + r * 2];
            float lc = ml_part[(base + c) * 32 + r * 2 + 1];
            float sf = __expf(mc - M);
            L += lc * sf;
            acc += sf * o_part[(base + c) * (16 * 64) + r * 64 + col];
        }
        out[((size_t)batch * SEQ + q0 + r) * HDIM + col] = acc / L;
    }
}

extern "C" void kernel_launch(void* const* d_in, const int* in_sizes, int n_in,
                              void* d_out, int out_size, void* d_ws, size_t ws_size,
                              hipStream_t stream) {
    const float* x  = (const float*)d_in[0];
    const float* Wq = (const float*)d_in[1];
    const float* bq = (const float*)d_in[2];
    const float* Wk = (const float*)d_in[3];
    const float* bk = (const float*)d_in[4];
    const float* Wv = (const float*)d_in[5];
    const float* bv = (const float*)d_in[6];
    float* out = (float*)d_out;

    h16* Wt = (h16*)d_ws;
    h16* Q  = Wt + WT_ELEMS;
    h16* K  = Q + QK_ELEMS;
    h16* Vt = K + QK_ELEMS;
    float* o_part  = (float*)(Vt + QK_ELEMS);
    float* ml_part = o_part + (size_t)NSLOT * 16 * 64;

    hipLaunchKernelGGL(prep_w, dim3(192), dim3(256), 0, stream, Wq, Wk, Wv, Wt);
    hipLaunchKernelGGL(qkv_proj, dim3(1024), dim3(256), 0, stream,
                       x, Wt, bq, bk, bv, Q, K, Vt);
    hipLaunchKernelGGL(flash, dim3(BATCH * NQT * MAXC), dim3(64), 0, stream,
                       Q, K, Vt, o_part, ml_part);
    hipLaunchKernelGGL(combine, dim3(BATCH * NQT), dim3(256), 0, stream,
                       o_part, ml_part, out);
}

// Round 3
// 218.198 us; speedup vs baseline: 1.3069x; 1.0249x over previous
//
#include <hip/hip_runtime.h>

#define BATCH 4
#define SEQ 4096
#define DMODEL 1024
#define HDIM 64
#define NQT 256      // q-tiles of 16 rows per batch
#define CHUNK 512    // KV positions per partial wave
#define MAXC 8       // max chunks per q-tile (SEQ/CHUNK)

typedef _Float16 h16;
typedef _Float16 h16x8 __attribute__((ext_vector_type(8)));
typedef float f32x4 __attribute__((ext_vector_type(4)));

#define WT_ELEMS (192 * DMODEL)
#define QK_ELEMS (BATCH * SEQ * HDIM)
#define NSLOT (BATCH * NQT * MAXC)

// ---------------- W transpose + fp16 convert: Wt[n][k] = W_sel[k][n%64] ----------------
__global__ __launch_bounds__(256) void prep_w(const float* __restrict__ Wq,
                                              const float* __restrict__ Wk,
                                              const float* __restrict__ Wv,
                                              h16* __restrict__ Wt) {
    int n = blockIdx.x;  // 0..191
    const float* W = (n < 64) ? Wq : (n < 128) ? Wk : Wv;
    int c = n & 63;
    for (int k = threadIdx.x; k < DMODEL; k += 256)
        Wt[n * DMODEL + k] = (h16)W[k * HDIM + c];
}

// ---------------- QKV projection GEMM: M=16384, K=1024, N=192 ----------------
__global__ __launch_bounds__(256) void qkv_proj(
    const float* __restrict__ x, const h16* __restrict__ Wt,
    const float* __restrict__ bq, const float* __restrict__ bk, const float* __restrict__ bv,
    h16* __restrict__ Q, h16* __restrict__ K, h16* __restrict__ Vt)
{
    int lane = threadIdx.x & 63;
    int w = threadIdx.x >> 6;
    int r0 = blockIdx.x * 16;
    int ln15 = lane & 15;
    int kc = (lane >> 4) * 8;

    f32x4 acc[3];
    #pragma unroll
    for (int f = 0; f < 3; f++) acc[f] = 0.f;

    #pragma unroll 2
    for (int k0 = 0; k0 < DMODEL; k0 += 32) {
        const float* xp = x + (size_t)(r0 + ln15) * DMODEL + k0 + kc;
        f32x4 lo = *(const f32x4*)xp;
        f32x4 hi = *(const f32x4*)(xp + 4);
        h16x8 av;
        #pragma unroll
        for (int j = 0; j < 4; j++) { av[j] = (h16)lo[j]; av[j + 4] = (h16)hi[j]; }
        h16x8 b[3];
        #pragma unroll
        for (int f = 0; f < 3; f++) {
            int col = 48 * w + 16 * f + ln15;
            b[f] = *(const h16x8*)(Wt + (size_t)col * DMODEL + k0 + kc);
        }
        #pragma unroll
        for (int f = 0; f < 3; f++)
            acc[f] = __builtin_amdgcn_mfma_f32_16x16x32_f16(av, b[f], acc[f], 0, 0, 0);
    }

    // epilogue: +bias, write Q,K row-major fp16; V transposed [B][H][T]
    #pragma unroll
    for (int f = 0; f < 3; f++) {
        int col = 48 * w + 16 * f + ln15;
        float bias = (col < 64) ? bq[col] : (col < 128) ? bk[col - 64] : bv[col - 128];
        #pragma unroll
        for (int i = 0; i < 4; i++) {
            int t = r0 + (lane >> 4) * 4 + i;
            int bb = t >> 12;
            int tt = t & (SEQ - 1);
            float v = acc[f][i] + bias;
            if (col < 64)
                Q[((size_t)bb * SEQ + tt) * HDIM + col] = (h16)v;
            else if (col < 128)
                K[((size_t)bb * SEQ + tt) * HDIM + (col - 64)] = (h16)v;
            else
                Vt[((size_t)bb * HDIM + (col - 128)) * SEQ + tt] = (h16)v;
        }
    }
}

// ---------------- causal flash attention partial ----------------
// block = 4 waves; wave w handles chunk (4*half + w) of one (batch, q-tile).
__global__ __launch_bounds__(256) void flash(
    const h16* __restrict__ Q, const h16* __restrict__ K, const h16* __restrict__ Vt,
    float* __restrict__ o_part, float* __restrict__ ml_part)
{
    __shared__ unsigned short plds[4][16 * 64];  // per-wave 2KB XOR-swizzled P tile
    int wid = threadIdx.x >> 6;
    int lane = threadIdx.x & 63;
    int bid = blockIdx.x;                 // grid = BATCH*NQT*2
    int half = bid & 1;
    int rest = bid >> 1;
    int qt = NQT - 1 - (rest & (NQT - 1));  // longest q-tiles dispatched first
    int batch = rest >> 8;
    int c = half * 4 + wid;
    int q0 = qt * 16;
    int nc = ((q0 + 15) >> 9) + 1;          // valid chunks for this q-tile
    if (c >= nc) return;

    int ln15 = lane & 15;
    int kc = (lane >> 4) * 8;
    int S = c * CHUNK;

    const h16* Qb = Q + (size_t)batch * SEQ * HDIM;
    const h16* Kb = K + (size_t)batch * SEQ * HDIM;
    const h16* Vb = Vt + (size_t)batch * HDIM * SEQ;

    h16x8 qa[2];
    #pragma unroll
    for (int cc = 0; cc < 2; cc++)
        qa[cc] = *(const h16x8*)(Qb + (size_t)(q0 + ln15) * HDIM + 32 * cc + kc);

    float m_i[4], l_i[4];
    f32x4 o[4];
    #pragma unroll
    for (int i = 0; i < 4; i++) { m_i[i] = -1e30f; l_i[i] = 0.f; }
    #pragma unroll
    for (int f = 0; f < 4; f++) o[f] = 0.f;

    int gdiag = (q0 + 15) >> 6;                                 // global diagonal tile
    int lt = (c == nc - 1) ? (gdiag - (S >> 6) + 1) : (CHUNK / 64);
    for (int t = 0; t < lt; t++) {
        int kt0 = S + t * 64;
        f32x4 sc[4];
        #pragma unroll
        for (int f = 0; f < 4; f++) sc[f] = 0.f;
        __builtin_amdgcn_s_setprio(1);
        #pragma unroll
        for (int cc = 0; cc < 2; cc++)
            #pragma unroll
            for (int f = 0; f < 4; f++) {
                h16x8 kb = *(const h16x8*)(Kb + (size_t)(kt0 + 16 * f + ln15) * HDIM + 32 * cc + kc);
                sc[f] = __builtin_amdgcn_mfma_f32_16x16x32_f16(qa[cc], kb, sc[f], 0, 0, 0);
            }
        __builtin_amdgcn_s_setprio(0);

        // scale + causal mask (only the global diagonal tile needs it)
        bool diag = ((S >> 6) + t) == gdiag;
        #pragma unroll
        for (int f = 0; f < 4; f++)
            #pragma unroll
            for (int i = 0; i < 4; i++) {
                float s = sc[f][i] * 0.125f;
                if (diag) {
                    int ktg = kt0 + 16 * f + ln15;
                    int qg = q0 + (lane >> 4) * 4 + i;
                    if (ktg > qg) s = -1e30f;
                }
                sc[f][i] = s;
            }

        // row max across the 16-lane col group
        float tm[4];
        #pragma unroll
        for (int i = 0; i < 4; i++)
            tm[i] = fmaxf(fmaxf(sc[0][i], sc[1][i]), fmaxf(sc[2][i], sc[3][i]));
        #pragma unroll
        for (int d = 1; d < 16; d <<= 1)
            #pragma unroll
            for (int i = 0; i < 4; i++) tm[i] = fmaxf(tm[i], __shfl_xor(tm[i], d));

        float al[4], rs[4];
        #pragma unroll
        for (int i = 0; i < 4; i++) {
            float mn = fmaxf(m_i[i], tm[i]);
            al[i] = __expf(m_i[i] - mn);
            m_i[i] = mn;
            rs[i] = 0.f;
        }

        // P = exp(s - m), row sums, store P to swizzled LDS as fp16
        #pragma unroll
        for (int f = 0; f < 4; f++)
            #pragma unroll
            for (int i = 0; i < 4; i++) {
                float p = __expf(sc[f][i] - m_i[i]);
                rs[i] += p;
                int row = (lane >> 4) * 4 + i;
                int byteoff = (row * 128 + (16 * f + ln15) * 2) ^ ((row & 7) << 4);
                *(h16*)((char*)plds[wid] + byteoff) = (h16)p;
            }
        #pragma unroll
        for (int d = 1; d < 16; d <<= 1)
            #pragma unroll
            for (int i = 0; i < 4; i++) rs[i] += __shfl_xor(rs[i], d);
        #pragma unroll
        for (int i = 0; i < 4; i++) l_i[i] = l_i[i] * al[i] + rs[i];
        #pragma unroll
        for (int f = 0; f < 4; f++)
            #pragma unroll
            for (int i = 0; i < 4; i++) o[f][i] *= al[i];

        asm volatile("s_waitcnt lgkmcnt(0)" ::: "memory");

        // PV: A = P (transposed via LDS), B = V via Vt (contiguous in t)
        __builtin_amdgcn_s_setprio(1);
        #pragma unroll
        for (int cc = 0; cc < 2; cc++) {
            int rb = (ln15 * 128 + (32 * cc + kc) * 2) ^ ((ln15 & 7) << 4);
            h16x8 pa = *(const h16x8*)((char*)plds[wid] + rb);
            #pragma unroll
            for (int f = 0; f < 4; f++) {
                h16x8 vb = *(const h16x8*)(Vb + (size_t)(16 * f + ln15) * SEQ + kt0 + 32 * cc + kc);
                o[f] = __builtin_amdgcn_mfma_f32_16x16x32_f16(pa, vb, o[f], 0, 0, 0);
            }
        }
        __builtin_amdgcn_s_setprio(0);
    }

    // write partial (unnormalized o, running m, l) for this chunk
    size_t slot = ((size_t)batch * NQT + qt) * MAXC + c;
    float* op = o_part + slot * (16 * 64);
    #pragma unroll
    for (int f = 0; f < 4; f++)
        #pragma unroll
        for (int i = 0; i < 4; i++) {
            int row = (lane >> 4) * 4 + i;
            op[row * 64 + 16 * f + ln15] = o[f][i];
        }
    if (ln15 == 0) {
        #pragma unroll
        for (int i = 0; i < 4; i++) {
            int row = (lane >> 4) * 4 + i;
            ml_part[slot * 32 + row * 2] = m_i[i];
            ml_part[slot * 32 + row * 2 + 1] = l_i[i];
        }
    }
}

// ---------------- combine partials: one block per (batch, q-tile) ----------------
__global__ __launch_bounds__(256) void combine(
    const float* __restrict__ o_part, const float* __restrict__ ml_part,
    float* __restrict__ out)
{
    int bid = blockIdx.x;           // batch*NQT + qt
    int batch = bid >> 8;
    int qt = bid & (NQT - 1);
    int q0 = qt * 16;
    int nc = ((q0 + 15) >> 9) + 1;
    int col = threadIdx.x & 63;
    int rg = threadIdx.x >> 6;      // 0..3
    size_t base = (size_t)bid * MAXC;

    #pragma unroll
    for (int j = 0; j < 4; j++) {
        int r = rg * 4 + j;
        float M = -1e30f;
        for (int c = 0; c < nc; c++)
            M = fmaxf(M, ml_part[(base + c) * 32 + r * 2]);
        float L = 0.f, acc = 0.f;
        for (int c = 0; c < nc; c++) {
            float mc = ml_part[(base + c) * 32 + r * 2];
            float lc = ml_part[(base + c) * 32 + r * 2 + 1];
            float sf = __expf(mc - M);
            L += lc * sf;
            acc += sf * o_part[(base + c) * (16 * 64) + r * 64 + col];
        }
        out[((size_t)batch * SEQ + q0 + r) * HDIM + col] = acc / L;
    }
}

extern "C" void kernel_launch(void* const* d_in, const int* in_sizes, int n_in,
                              void* d_out, int out_size, void* d_ws, size_t ws_size,
                              hipStream_t stream) {
    const float* x  = (const float*)d_in[0];
    const float* Wq = (const float*)d_in[1];
    const float* bq = (const float*)d_in[2];
    const float* Wk = (const float*)d_in[3];
    const float* bk = (const float*)d_in[4];
    const float* Wv = (const float*)d_in[5];
    const float* bv = (const float*)d_in[6];
    float* out = (float*)d_out;

    h16* Wt = (h16*)d_ws;
    h16* Q  = Wt + WT_ELEMS;
    h16* K  = Q + QK_ELEMS;
    h16* Vt = K + QK_ELEMS;
    float* o_part  = (float*)(Vt + QK_ELEMS);
    float* ml_part = o_part + (size_t)NSLOT * 16 * 64;

    hipLaunchKernelGGL(prep_w, dim3(192), dim3(256), 0, stream, Wq, Wk, Wv, Wt);
    hipLaunchKernelGGL(qkv_proj, dim3(1024), dim3(256), 0, stream,
                       x, Wt, bq, bk, bv, Q, K, Vt);
    hipLaunchKernelGGL(flash, dim3(BATCH * NQT * 2), dim3(256), 0, stream,
                       Q, K, Vt, o_part, ml_part);
    hipLaunchKernelGGL(combine, dim3(BATCH * NQT), dim3(256), 0, stream,
                       o_part, ml_part, out);
}

// Round 6
// 217.996 us; speedup vs baseline: 1.3081x; 1.0009x over previous
//
#include <hip/hip_runtime.h>

#define BATCH 4
#define SEQ 4096
#define DMODEL 1024
#define HDIM 64

#define QBLK 32      // q rows per wave
#define NQT 128      // 32-row q-tiles per batch
#define CHUNK 256    // KV positions per wave
#define ITERS 8      // CHUNK / 32
#define BSLOT 1088   // per-batch valid (qt,chunk) slots = sum_qt (qt/8 + 1)

typedef _Float16 h16;
typedef _Float16 h16x8 __attribute__((ext_vector_type(8)));
typedef _Float16 h16x4 __attribute__((ext_vector_type(4)));
typedef float f32x4 __attribute__((ext_vector_type(4)));
typedef float f32x16 __attribute__((ext_vector_type(16)));

#define WT_ELEMS (192 * DMODEL)
#define QK_ELEMS (BATCH * SEQ * HDIM)
#define NSLOT (BATCH * BSLOT)

// valid-slot prefix: qt = 8a+b -> sum_{q<qt} (q/8+1) = (a+1)(4a+b)
__device__ __forceinline__ int slot_base(int qt) {
    int a = qt >> 3, b = qt & 7;
    return (a + 1) * (4 * a + b);
}

// ---------------- W transpose + fp16 convert: Wt[n][k] = W_sel[k][n%64] ----------------
__global__ __launch_bounds__(256) void prep_w(const float* __restrict__ Wq,
                                              const float* __restrict__ Wk,
                                              const float* __restrict__ Wv,
                                              h16* __restrict__ Wt) {
    int n = blockIdx.x;  // 0..191
    const float* W = (n < 64) ? Wq : (n < 128) ? Wk : Wv;
    int c = n & 63;
    for (int k = threadIdx.x; k < DMODEL; k += 256)
        Wt[n * DMODEL + k] = (h16)W[k * HDIM + c];
}

// ---------------- QKV projection GEMM: M=16384, K=1024, N=192 ----------------
// grid 512 (32-row tiles); 4 waves: wave w -> 48 N-cols. 2 M-frags x 3 N-frags.
// Q is written pre-scaled by 1/8 (softmax scale folded in).
__global__ __launch_bounds__(256) void qkv_proj(
    const float* __restrict__ x, const h16* __restrict__ Wt,
    const float* __restrict__ bq, const float* __restrict__ bk, const float* __restrict__ bv,
    h16* __restrict__ Q, h16* __restrict__ K, h16* __restrict__ Vt)
{
    int lane = threadIdx.x & 63;
    int w = threadIdx.x >> 6;
    int r0 = blockIdx.x * 32;
    int ln15 = lane & 15;
    int kc = (lane >> 4) * 8;

    f32x4 acc[2][3];
    #pragma unroll
    for (int m = 0; m < 2; m++)
        #pragma unroll
        for (int f = 0; f < 3; f++) acc[m][f] = 0.f;

    #pragma unroll 2
    for (int k0 = 0; k0 < DMODEL; k0 += 32) {
        h16x8 a[2];
        #pragma unroll
        for (int m = 0; m < 2; m++) {
            const float* xp = x + (size_t)(r0 + 16 * m + ln15) * DMODEL + k0 + kc;
            f32x4 lo = *(const f32x4*)xp;
            f32x4 hi = *(const f32x4*)(xp + 4);
            h16x8 av;
            #pragma unroll
            for (int j = 0; j < 4; j++) { av[j] = (h16)lo[j]; av[j + 4] = (h16)hi[j]; }
            a[m] = av;
        }
        h16x8 b[3];
        #pragma unroll
        for (int f = 0; f < 3; f++) {
            int col = 48 * w + 16 * f + ln15;
            b[f] = *(const h16x8*)(Wt + (size_t)col * DMODEL + k0 + kc);
        }
        #pragma unroll
        for (int m = 0; m < 2; m++)
            #pragma unroll
            for (int f = 0; f < 3; f++)
                acc[m][f] = __builtin_amdgcn_mfma_f32_16x16x32_f16(a[m], b[f], acc[m][f], 0, 0, 0);
    }

    #pragma unroll
    for (int f = 0; f < 3; f++) {
        int col = 48 * w + 16 * f + ln15;
        float bias = (col < 64) ? bq[col] : (col < 128) ? bk[col - 64] : bv[col - 128];
        #pragma unroll
        for (int m = 0; m < 2; m++) {
            #pragma unroll
            for (int i = 0; i < 4; i++) {
                int t = r0 + 16 * m + (lane >> 4) * 4 + i;
                int bb = t >> 12;
                int tt = t & (SEQ - 1);
                float v = acc[m][f][i] + bias;
                if (col < 64)
                    Q[((size_t)bb * SEQ + tt) * HDIM + col] = (h16)(v * 0.125f);
                else if (col < 128)
                    K[((size_t)bb * SEQ + tt) * HDIM + (col - 64)] = (h16)v;
                else
                    Vt[((size_t)bb * HDIM + (col - 128)) * SEQ + tt] = (h16)v;
            }
        }
    }
}

// ---------------- causal flash attention partial: all-register, 32x32 MFMA ----------------
// Wave owns (batch, 32 q-rows, 256 kv). Swapped QK -> S^T: lane holds q = lane&31 on the
// OUTPUT COLUMN, k = (r&3)+8*(r>>2)+4*hi per reg r. PV keeps q on the column by putting
// V as the A operand and P as the B operand: O^T = V^T . P, so the per-lane softmax state
// (m,l for q=lane&31) applies directly to all 16 accumulator regs. No LDS, no barriers.
__global__ __launch_bounds__(256) void flash(
    const h16* __restrict__ Q, const h16* __restrict__ K, const h16* __restrict__ Vt,
    h16* __restrict__ o_part, float* __restrict__ ml_part)
{
    int wid = threadIdx.x >> 6;
    int lane = threadIdx.x & 63;
    int bid = blockIdx.x;                  // grid = BATCH*NQT*4
    int quarter = bid & 3;
    int rest = bid >> 2;
    int qtidx = rest & (NQT - 1);
    int batch = rest >> 7;
    int qt = NQT - 1 - qtidx;              // longest q-tiles first
    int c = quarter * 4 + wid;
    int nc = (qt >> 3) + 1;                // chunks covering [0, q0+31]
    if (c >= nc) return;

    int q0 = qt * QBLK;
    int S = c * CHUNK;
    int l31 = lane & 31;
    int hi = lane >> 5;
    int qg = q0 + l31;

    const h16* Qb = Q + (size_t)batch * SEQ * HDIM;
    const h16* Kb = K + (size_t)batch * SEQ * HDIM;
    const h16* Vb = Vt + (size_t)batch * HDIM * SEQ;

    h16x8 qb[4];
    #pragma unroll
    for (int d = 0; d < 4; d++)
        qb[d] = *(const h16x8*)(Qb + (size_t)(q0 + l31) * HDIM + 16 * d + 8 * hi);

    f32x16 o[2];
    #pragma unroll
    for (int m = 0; m < 2; m++)
        #pragma unroll
        for (int r = 0; r < 16; r++) o[m][r] = 0.f;
    float m_i = -1e30f, l_i = 0.f;

    for (int t = 0; t < ITERS; t++) {
        int kt0 = S + 32 * t;
        h16x8 ka[4];
        #pragma unroll
        for (int d = 0; d < 4; d++)
            ka[d] = *(const h16x8*)(Kb + (size_t)(kt0 + l31) * HDIM + 16 * d + 8 * hi);

        f32x16 s;
        #pragma unroll
        for (int r = 0; r < 16; r++) s[r] = 0.f;
        __builtin_amdgcn_s_setprio(1);
        #pragma unroll
        for (int d = 0; d < 4; d++)
            s = __builtin_amdgcn_mfma_f32_32x32x16_f16(ka[d], qb[d], s, 0, 0, 0);
        __builtin_amdgcn_s_setprio(0);

        float sc[16];
        #pragma unroll
        for (int r = 0; r < 16; r++) sc[r] = s[r];
        if (kt0 + 31 > q0) {  // tile may contain masked entries (wave-uniform)
            #pragma unroll
            for (int r = 0; r < 16; r++) {
                int kg = kt0 + (r & 3) + 8 * (r >> 2) + 4 * hi;
                if (kg > qg) sc[r] = -1e30f;
            }
        }
        float tm = sc[0];
        #pragma unroll
        for (int r = 1; r < 16; r++) tm = fmaxf(tm, sc[r]);
        tm = fmaxf(tm, __shfl_xor(tm, 32));
        float mn = fmaxf(m_i, tm);
        float al = __expf(m_i - mn);
        m_i = mn;
        float p[16], rs = 0.f;
        #pragma unroll
        for (int r = 0; r < 16; r++) { p[r] = __expf(sc[r] - mn); rs += p[r]; }
        rs += __shfl_xor(rs, 32);
        l_i = l_i * al + rs;
        #pragma unroll
        for (int m = 0; m < 2; m++)
            #pragma unroll
            for (int r = 0; r < 16; r++) o[m][r] *= al;

        // pack P in natural register order; as the B operand its element-j placement
        // (j&3)+8*(j>>2)+4*hi matches the C/D row formula, so no shuffling needed.
        h16x8 pb0, pb1;
        #pragma unroll
        for (int j = 0; j < 8; j++) { pb0[j] = (h16)p[j]; pb1[j] = (h16)p[8 + j]; }

        // V as the A operand: lane's row = h = 32*m + l31; element j of step s ->
        //   V[kt0 + 16*s + 4*hi + (j&3) + 8*(j>>2)][h]  (same k-formula as P)
        __builtin_amdgcn_s_setprio(1);
        #pragma unroll
        for (int m = 0; m < 2; m++) {
            const h16* vrow = Vb + (size_t)(32 * m + l31) * SEQ + kt0 + 4 * hi;
            h16x4 va = *(const h16x4*)(vrow);
            h16x4 vbb = *(const h16x4*)(vrow + 8);
            h16x4 vcc = *(const h16x4*)(vrow + 16);
            h16x4 vdd = *(const h16x4*)(vrow + 24);
            h16x8 vb0 = {va[0], va[1], va[2], va[3], vbb[0], vbb[1], vbb[2], vbb[3]};
            h16x8 vb1 = {vcc[0], vcc[1], vcc[2], vcc[3], vdd[0], vdd[1], vdd[2], vdd[3]};
            o[m] = __builtin_amdgcn_mfma_f32_32x32x16_f16(vb0, pb0, o[m], 0, 0, 0);
            o[m] = __builtin_amdgcn_mfma_f32_32x32x16_f16(vb1, pb1, o[m], 0, 0, 0);
        }
        __builtin_amdgcn_s_setprio(0);
    }

    // write l-normalized partial (f16) + (m, l) f32.
    // o[m][r] = O[q = q0+l31][h = 32*m + crow(r,hi)] (unnormalized); lane's l_i matches q.
    float inv = 1.f / l_i;
    size_t slot = (size_t)batch * BSLOT + slot_base(qt) + c;
    h16* op = o_part + slot * (QBLK * 64);
    #pragma unroll
    for (int m = 0; m < 2; m++)
        #pragma unroll
        for (int r = 0; r < 16; r++) {
            int hcol = 32 * m + (r & 3) + 8 * (r >> 2) + 4 * hi;
            op[l31 * 64 + hcol] = (h16)(o[m][r] * inv);
        }
    if (hi == 0) {
        ml_part[slot * 64 + l31 * 2] = m_i;
        ml_part[slot * 64 + l31 * 2 + 1] = l_i;
    }
}

// ---------------- combine partials: one block per (batch, 32-row q-tile) ----------------
__global__ __launch_bounds__(256) void combine(
    const h16* __restrict__ o_part, const float* __restrict__ ml_part,
    float* __restrict__ out)
{
    int bid = blockIdx.x;           // batch*NQT + qt
    int batch = bid >> 7;
    int qt = bid & (NQT - 1);
    int q0 = qt * QBLK;
    int nc = (qt >> 3) + 1;
    int col = threadIdx.x & 63;
    int rg = threadIdx.x >> 6;      // 0..3 -> rows rg*8..rg*8+7
    size_t base = (size_t)batch * BSLOT + slot_base(qt);

    #pragma unroll
    for (int j = 0; j < 8; j++) {
        int r = rg * 8 + j;
        float M = -1e30f;
        for (int c = 0; c < nc; c++)
            M = fmaxf(M, ml_part[(base + c) * 64 + r * 2]);
        float L = 0.f, acc = 0.f;
        for (int c = 0; c < nc; c++) {
            float mc = ml_part[(base + c) * 64 + r * 2];
            float lc = ml_part[(base + c) * 64 + r * 2 + 1];
            float wgt = __expf(mc - M) * lc;
            L += wgt;
            acc += wgt * (float)o_part[(base + c) * (QBLK * 64) + r * 64 + col];
        }
        out[((size_t)batch * SEQ + q0 + r) * HDIM + col] = acc / L;
    }
}

extern "C" void kernel_launch(void* const* d_in, const int* in_sizes, int n_in,
                              void* d_out, int out_size, void* d_ws, size_t ws_size,
                              hipStream_t stream) {
    const float* x  = (const float*)d_in[0];
    const float* Wq = (const float*)d_in[1];
    const float* bq = (const float*)d_in[2];
    const float* Wk = (const float*)d_in[3];
    const float* bk = (const float*)d_in[4];
    const float* Wv = (const float*)d_in[5];
    const float* bv = (const float*)d_in[6];
    float* out = (float*)d_out;

    h16* Wt = (h16*)d_ws;
    h16* Q  = Wt + WT_ELEMS;
    h16* K  = Q + QK_ELEMS;
    h16* Vt = K + QK_ELEMS;
    h16* o_part = Vt + QK_ELEMS;
    float* ml_part = (float*)(o_part + (size_t)NSLOT * QBLK * 64);
    // total ws ~= 24.4 MiB

    hipLaunchKernelGGL(prep_w, dim3(192), dim3(256), 0, stream, Wq, Wk, Wv, Wt);
    hipLaunchKernelGGL(qkv_proj, dim3(512), dim3(256), 0, stream,
                       x, Wt, bq, bk, bv, Q, K, Vt);
    hipLaunchKernelGGL(flash, dim3(BATCH * NQT * 4), dim3(256), 0, stream,
                       Q, K, Vt, o_part, ml_part);
    hipLaunchKernelGGL(combine, dim3(BATCH * NQT), dim3(256), 0, stream,
                       o_part, ml_part, out);
}

// Round 7
// 158.891 us; speedup vs baseline: 1.7947x; 1.3720x over previous
//
#include <hip/hip_runtime.h>

#define BATCH 4
#define SEQ 4096
#define DMODEL 1024
#define HDIM 64

#define QBLK 32      // q rows per wave
#define NQT 128      // 32-row q-tiles per batch
#define CHUNK 256    // KV positions per wave
#define ITERS 8      // CHUNK / 32
#define BSLOT 1088   // per-batch valid (qt,chunk) slots = sum_qt (qt/8 + 1)

typedef _Float16 h16;
typedef _Float16 h16x8 __attribute__((ext_vector_type(8)));
typedef _Float16 h16x4 __attribute__((ext_vector_type(4)));
typedef float f32x4 __attribute__((ext_vector_type(4)));
typedef float f32x16 __attribute__((ext_vector_type(16)));

#define WT_ELEMS (192 * DMODEL)
#define QK_ELEMS (BATCH * SEQ * HDIM)       // 1048576
#define XH_ELEMS (BATCH * SEQ * DMODEL)     // 16777216
#define NSLOT (BATCH * BSLOT)

// valid-slot prefix: qt = 8a+b -> sum_{q<qt} (q/8+1) = (a+1)(4a+b)
__device__ __forceinline__ int slot_base(int qt) {
    int a = qt >> 3, b = qt & 7;
    return (a + 1) * (4 * a + b);
}

// k-slot permutation for MFMA A/B fragments: swap bits 2<->3 (self-inverse)
__device__ __forceinline__ int kperm(int u) {
    return (u & 3) | (((u >> 2) & 1) << 3) | (((u >> 3) & 1) << 2);
}

// ---------------- fused prep: Wt transpose+cvt (blocks 0..191), x->f16 (rest) ----------------
__global__ __launch_bounds__(256) void prep(const float* __restrict__ Wq,
                                            const float* __restrict__ Wk,
                                            const float* __restrict__ Wv,
                                            const float* __restrict__ x,
                                            h16* __restrict__ Wt,
                                            h16* __restrict__ xh) {
    int b = blockIdx.x;
    if (b < 192) {
        const float* W = (b < 64) ? Wq : (b < 128) ? Wk : Wv;
        int c = b & 63;
        for (int k = threadIdx.x; k < DMODEL; k += 256)
            Wt[b * DMODEL + k] = (h16)W[k * HDIM + c];
        return;
    }
    // x -> f16, grid-stride over 8-elem chunks, fully coalesced
    size_t gtid = (size_t)(b - 192) * 256 + threadIdx.x;   // 0 .. 524287
    #pragma unroll
    for (int i = 0; i < 4; i++) {
        size_t off = (gtid + (size_t)i * 524288) * 8;
        f32x4 lo = *(const f32x4*)(x + off);
        f32x4 hi = *(const f32x4*)(x + off + 4);
        h16x8 v;
        #pragma unroll
        for (int j = 0; j < 4; j++) { v[j] = (h16)lo[j]; v[j + 4] = (h16)hi[j]; }
        *(h16x8*)(xh + off) = v;
    }
}

// ---------------- QKV projection GEMM: M=16384, K=1024, N=192, f16 inputs ----------------
// grid 512 (32-row tiles); 4 waves: wave w -> 48 N-cols. 2 M-frags x 3 N-frags.
// Q pre-scaled by 1/8; V stored time-permuted (kperm within 16-groups) for flash.
__global__ __launch_bounds__(256) void qkv_proj(
    const h16* __restrict__ xh, const h16* __restrict__ Wt,
    const float* __restrict__ bq, const float* __restrict__ bk, const float* __restrict__ bv,
    h16* __restrict__ Q, h16* __restrict__ K, h16* __restrict__ Vt)
{
    int lane = threadIdx.x & 63;
    int w = threadIdx.x >> 6;
    int r0 = blockIdx.x * 32;
    int ln15 = lane & 15;
    int kc = (lane >> 4) * 8;

    f32x4 acc[2][3];
    #pragma unroll
    for (int m = 0; m < 2; m++)
        #pragma unroll
        for (int f = 0; f < 3; f++) acc[m][f] = 0.f;

    #pragma unroll 4
    for (int k0 = 0; k0 < DMODEL; k0 += 32) {
        h16x8 a[2], b[3];
        #pragma unroll
        for (int m = 0; m < 2; m++)
            a[m] = *(const h16x8*)(xh + (size_t)(r0 + 16 * m + ln15) * DMODEL + k0 + kc);
        #pragma unroll
        for (int f = 0; f < 3; f++) {
            int col = 48 * w + 16 * f + ln15;
            b[f] = *(const h16x8*)(Wt + (size_t)col * DMODEL + k0 + kc);
        }
        #pragma unroll
        for (int m = 0; m < 2; m++)
            #pragma unroll
            for (int f = 0; f < 3; f++)
                acc[m][f] = __builtin_amdgcn_mfma_f32_16x16x32_f16(a[m], b[f], acc[m][f], 0, 0, 0);
    }

    #pragma unroll
    for (int f = 0; f < 3; f++) {
        int col = 48 * w + 16 * f + ln15;
        float bias = (col < 64) ? bq[col] : (col < 128) ? bk[col - 64] : bv[col - 128];
        #pragma unroll
        for (int m = 0; m < 2; m++) {
            #pragma unroll
            for (int i = 0; i < 4; i++) {
                int t = r0 + 16 * m + (lane >> 4) * 4 + i;
                int bb = t >> 12;
                int tt = t & (SEQ - 1);
                float v = acc[m][f][i] + bias;
                if (col < 64)
                    Q[((size_t)bb * SEQ + tt) * HDIM + col] = (h16)(v * 0.125f);
                else if (col < 128)
                    K[((size_t)bb * SEQ + tt) * HDIM + (col - 64)] = (h16)v;
                else {
                    int tp = (tt & ~15) | kperm(tt & 15);
                    Vt[((size_t)bb * HDIM + (col - 128)) * SEQ + tp] = (h16)v;
                }
            }
        }
    }
}

// ---------------- causal flash attention partial: all-register, 32x32 MFMA ----------------
// Wave owns (batch, 32 q-rows, 256 kv). Swapped QK -> q on output column (lane&31).
// PV: V as A operand (pre-permuted Vt -> contiguous 16B loads), P as B operand.
// Double-buffered K/V registers, all of t+1's loads issued before t's softmax.
__global__ __launch_bounds__(256, 2) void flash(
    const h16* __restrict__ Q, const h16* __restrict__ K, const h16* __restrict__ Vt,
    h16* __restrict__ o_part, float* __restrict__ ml_part)
{
    int wid = threadIdx.x >> 6;
    int lane = threadIdx.x & 63;
    int bid = blockIdx.x;                  // grid = BATCH*NQT*4
    int quarter = bid & 3;
    int rest = bid >> 2;
    int qtidx = rest & (NQT - 1);
    int batch = rest >> 7;
    int qt = NQT - 1 - qtidx;              // longest q-tiles first
    int c = quarter * 4 + wid;
    int nc = (qt >> 3) + 1;
    if (c >= nc) return;

    int q0 = qt * QBLK;
    int S = c * CHUNK;
    int l31 = lane & 31;
    int hi = lane >> 5;
    int qg = q0 + l31;

    const h16* Qb = Q + (size_t)batch * SEQ * HDIM;
    const h16* Kb = K + (size_t)batch * SEQ * HDIM;
    const h16* Vb = Vt + (size_t)batch * HDIM * SEQ;
    const h16* krow = Kb + (size_t)l31 * HDIM + 8 * hi;
    const h16* vrow0 = Vb + (size_t)l31 * SEQ + 8 * hi;
    const h16* vrow1 = Vb + (size_t)(32 + l31) * SEQ + 8 * hi;

    h16x8 qb[4];
    #pragma unroll
    for (int d = 0; d < 4; d++)
        qb[d] = *(const h16x8*)(Qb + (size_t)(q0 + l31) * HDIM + 16 * d + 8 * hi);

    f32x16 o[2];
    #pragma unroll
    for (int m = 0; m < 2; m++)
        #pragma unroll
        for (int r = 0; r < 16; r++) o[m][r] = 0.f;
    float m_i = -1e30f, l_i = 0.f;

    h16x8 ka[2][4], va[2][4];
    #pragma unroll
    for (int d = 0; d < 4; d++)
        ka[0][d] = *(const h16x8*)(krow + (size_t)S * HDIM + 16 * d);
    va[0][0] = *(const h16x8*)(vrow0 + S);
    va[0][1] = *(const h16x8*)(vrow0 + S + 16);
    va[0][2] = *(const h16x8*)(vrow1 + S);
    va[0][3] = *(const h16x8*)(vrow1 + S + 16);

    #pragma unroll
    for (int t = 0; t < ITERS; t++) {
        int cur = t & 1, nxt = cur ^ 1;
        int kt0 = S + 32 * t;

        f32x16 s;
        #pragma unroll
        for (int r = 0; r < 16; r++) s[r] = 0.f;
        __builtin_amdgcn_s_setprio(1);
        #pragma unroll
        for (int d = 0; d < 4; d++)
            s = __builtin_amdgcn_mfma_f32_32x32x16_f16(ka[cur][d], qb[d], s, 0, 0, 0);
        __builtin_amdgcn_s_setprio(0);

        // prefetch t+1 (compile-time guarded; all 8 loads in flight over softmax+PV)
        if (t + 1 < ITERS) {
            int kn = kt0 + 32;
            #pragma unroll
            for (int d = 0; d < 4; d++)
                ka[nxt][d] = *(const h16x8*)(krow + (size_t)kn * HDIM + 16 * d);
            va[nxt][0] = *(const h16x8*)(vrow0 + kn);
            va[nxt][1] = *(const h16x8*)(vrow0 + kn + 16);
            va[nxt][2] = *(const h16x8*)(vrow1 + kn);
            va[nxt][3] = *(const h16x8*)(vrow1 + kn + 16);
        }

        float sc[16];
        #pragma unroll
        for (int r = 0; r < 16; r++) sc[r] = s[r];
        if (kt0 + 31 > q0) {  // tile may contain masked entries
            #pragma unroll
            for (int r = 0; r < 16; r++) {
                int kg = kt0 + (r & 3) + 8 * (r >> 2) + 4 * hi;
                if (kg > qg) sc[r] = -1e30f;
            }
        }
        float tm = sc[0];
        #pragma unroll
        for (int r = 1; r < 16; r++) tm = fmaxf(tm, sc[r]);
        tm = fmaxf(tm, __shfl_xor(tm, 32));
        float mn = fmaxf(m_i, tm);
        float al = __expf(m_i - mn);
        m_i = mn;
        float p[16], rs = 0.f;
        #pragma unroll
        for (int r = 0; r < 16; r++) { p[r] = __expf(sc[r] - mn); rs += p[r]; }
        rs += __shfl_xor(rs, 32);
        l_i = l_i * al + rs;
        #pragma unroll
        for (int m = 0; m < 2; m++)
            #pragma unroll
            for (int r = 0; r < 16; r++) o[m][r] *= al;

        h16x8 pb0, pb1;
        #pragma unroll
        for (int j = 0; j < 8; j++) { pb0[j] = (h16)p[j]; pb1[j] = (h16)p[8 + j]; }

        __builtin_amdgcn_s_setprio(1);
        o[0] = __builtin_amdgcn_mfma_f32_32x32x16_f16(va[cur][0], pb0, o[0], 0, 0, 0);
        o[0] = __builtin_amdgcn_mfma_f32_32x32x16_f16(va[cur][1], pb1, o[0], 0, 0, 0);
        o[1] = __builtin_amdgcn_mfma_f32_32x32x16_f16(va[cur][2], pb0, o[1], 0, 0, 0);
        o[1] = __builtin_amdgcn_mfma_f32_32x32x16_f16(va[cur][3], pb1, o[1], 0, 0, 0);
        __builtin_amdgcn_s_setprio(0);
    }

    // write l-normalized partial (f16, 4-wide packed stores) + (m, l) f32
    float inv = 1.f / l_i;
    size_t slot = (size_t)batch * BSLOT + slot_base(qt) + c;
    h16* op = o_part + slot * (QBLK * 64) + l31 * 64;
    #pragma unroll
    for (int m = 0; m < 2; m++)
        #pragma unroll
        for (int q = 0; q < 4; q++) {
            h16x4 pk;
            #pragma unroll
            for (int i = 0; i < 4; i++) pk[i] = (h16)(o[m][4 * q + i] * inv);
            *(h16x4*)(op + 32 * m + 8 * q + 4 * hi) = pk;
        }
    if (hi == 0) {
        ml_part[slot * 64 + l31 * 2] = m_i;
        ml_part[slot * 64 + l31 * 2 + 1] = l_i;
    }
}

// ---------------- combine partials: one block per (batch, qt, row-half) ----------------
__global__ __launch_bounds__(256) void combine(
    const h16* __restrict__ o_part, const float* __restrict__ ml_part,
    float* __restrict__ out)
{
    int bid = blockIdx.x;           // BATCH*NQT*2
    int rh = bid & 1;
    int tile = bid >> 1;
    int batch = tile >> 7;
    int qt = tile & (NQT - 1);
    int q0 = qt * QBLK;
    int nc = (qt >> 3) + 1;
    int col = threadIdx.x & 63;
    int rg = threadIdx.x >> 6;      // 0..3
    size_t base = (size_t)batch * BSLOT + slot_base(qt);

    #pragma unroll
    for (int j = 0; j < 4; j++) {
        int r = rh * 16 + rg * 4 + j;
        float M = -1e30f;
        for (int c = 0; c < nc; c++)
            M = fmaxf(M, ml_part[(base + c) * 64 + r * 2]);
        float L = 0.f, acc = 0.f;
        for (int c = 0; c < nc; c++) {
            float mc = ml_part[(base + c) * 64 + r * 2];
            float lc = ml_part[(base + c) * 64 + r * 2 + 1];
            float wgt = __expf(mc - M) * lc;
            L += wgt;
            acc += wgt * (float)o_part[(base + c) * (QBLK * 64) + r * 64 + col];
        }
        out[((size_t)batch * SEQ + q0 + r) * HDIM + col] = acc / L;
    }
}

extern "C" void kernel_launch(void* const* d_in, const int* in_sizes, int n_in,
                              void* d_out, int out_size, void* d_ws, size_t ws_size,
                              hipStream_t stream) {
    const float* x  = (const float*)d_in[0];
    const float* Wq = (const float*)d_in[1];
    const float* bq = (const float*)d_in[2];
    const float* Wk = (const float*)d_in[3];
    const float* bk = (const float*)d_in[4];
    const float* Wv = (const float*)d_in[5];
    const float* bv = (const float*)d_in[6];
    float* out = (float*)d_out;

    h16* Wt = (h16*)d_ws;
    h16* Q  = Wt + WT_ELEMS;
    h16* K  = Q + QK_ELEMS;
    h16* Vt = K + QK_ELEMS;
    h16* xh = Vt + QK_ELEMS;             // 32 MB, dead after qkv_proj
    h16* o_part = xh;                    // aliases xh (flash phase)
    float* ml_part = (float*)(o_part + (size_t)NSLOT * QBLK * 64);
    // peak ws use: 0.4 + 3*2 + 32 MB = 38.4 MiB (< R3-proven 41.3e6 B)

    hipLaunchKernelGGL(prep, dim3(192 + 2048), dim3(256), 0, stream, Wq, Wk, Wv, x, Wt, xh);
    hipLaunchKernelGGL(qkv_proj, dim3(512), dim3(256), 0, stream,
                       xh, Wt, bq, bk, bv, Q, K, Vt);
    hipLaunchKernelGGL(flash, dim3(BATCH * NQT * 4), dim3(256), 0, stream,
                       Q, K, Vt, o_part, ml_part);
    hipLaunchKernelGGL(combine, dim3(BATCH * NQT * 2), dim3(256), 0, stream,
                       o_part, ml_part, out);
}

// Round 8
// 157.999 us; speedup vs baseline: 1.8048x; 1.0056x over previous
//
#include <hip/hip_runtime.h>

#define BATCH 4
#define SEQ 4096
#define DMODEL 1024
#define HDIM 64

#define QBLK 32      // q rows per wave
#define NQT 128      // 32-row q-tiles per batch
#define CHUNK 256    // KV positions per wave
#define ITERS 8      // CHUNK / 32
#define BSLOT 1088   // per-batch valid (qt,chunk) slots = sum_qt (qt/8 + 1)

typedef _Float16 h16;
typedef _Float16 h16x8 __attribute__((ext_vector_type(8)));
typedef _Float16 h16x4 __attribute__((ext_vector_type(4)));
typedef float f32x4 __attribute__((ext_vector_type(4)));
typedef float f32x16 __attribute__((ext_vector_type(16)));

#define WT_ELEMS (192 * DMODEL)
#define QK_ELEMS (BATCH * SEQ * HDIM)       // 1048576
#define NSLOT (BATCH * BSLOT)

// valid-slot prefix: qt = 8a+b -> sum_{q<qt} (q/8+1) = (a+1)(4a+b)
__device__ __forceinline__ int slot_base(int qt) {
    int a = qt >> 3, b = qt & 7;
    return (a + 1) * (4 * a + b);
}

// k-slot permutation for MFMA A/B fragments: swap bits 2<->3 (self-inverse)
__device__ __forceinline__ int kperm(int u) {
    return (u & 3) | (((u >> 2) & 1) << 3) | (((u >> 3) & 1) << 2);
}

// compiler-proof async load: issue global_load_dwordx4, completion via explicit vmcnt
__device__ __forceinline__ void gload(h16x8& dst, const h16* p) {
    asm volatile("global_load_dwordx4 %0, %1, off" : "=v"(dst) : "v"(p));
}

// ---------------- fused prep: Wt transpose+cvt (blocks 0..191), x->f16 (rest) ----------------
__global__ __launch_bounds__(256) void prep(const float* __restrict__ Wq,
                                            const float* __restrict__ Wk,
                                            const float* __restrict__ Wv,
                                            const float* __restrict__ x,
                                            h16* __restrict__ Wt,
                                            h16* __restrict__ xh) {
    int b = blockIdx.x;
    if (b < 192) {
        const float* W = (b < 64) ? Wq : (b < 128) ? Wk : Wv;
        int c = b & 63;
        for (int k = threadIdx.x; k < DMODEL; k += 256)
            Wt[b * DMODEL + k] = (h16)W[k * HDIM + c];
        return;
    }
    size_t gtid = (size_t)(b - 192) * 256 + threadIdx.x;   // 0 .. 524287
    #pragma unroll
    for (int i = 0; i < 4; i++) {
        size_t off = (gtid + (size_t)i * 524288) * 8;
        f32x4 lo = *(const f32x4*)(x + off);
        f32x4 hi = *(const f32x4*)(x + off + 4);
        h16x8 v;
        #pragma unroll
        for (int j = 0; j < 4; j++) { v[j] = (h16)lo[j]; v[j + 4] = (h16)hi[j]; }
        *(h16x8*)(xh + off) = v;
    }
}

// ---------------- QKV projection GEMM: M=16384, K=1024, N=192, f16 inputs ----------------
__global__ __launch_bounds__(256) void qkv_proj(
    const h16* __restrict__ xh, const h16* __restrict__ Wt,
    const float* __restrict__ bq, const float* __restrict__ bk, const float* __restrict__ bv,
    h16* __restrict__ Q, h16* __restrict__ K, h16* __restrict__ Vt)
{
    int lane = threadIdx.x & 63;
    int w = threadIdx.x >> 6;
    int r0 = blockIdx.x * 32;
    int ln15 = lane & 15;
    int kc = (lane >> 4) * 8;

    f32x4 acc[2][3];
    #pragma unroll
    for (int m = 0; m < 2; m++)
        #pragma unroll
        for (int f = 0; f < 3; f++) acc[m][f] = 0.f;

    #pragma unroll 4
    for (int k0 = 0; k0 < DMODEL; k0 += 32) {
        h16x8 a[2], b[3];
        #pragma unroll
        for (int m = 0; m < 2; m++)
            a[m] = *(const h16x8*)(xh + (size_t)(r0 + 16 * m + ln15) * DMODEL + k0 + kc);
        #pragma unroll
        for (int f = 0; f < 3; f++) {
            int col = 48 * w + 16 * f + ln15;
            b[f] = *(const h16x8*)(Wt + (size_t)col * DMODEL + k0 + kc);
        }
        #pragma unroll
        for (int m = 0; m < 2; m++)
            #pragma unroll
            for (int f = 0; f < 3; f++)
                acc[m][f] = __builtin_amdgcn_mfma_f32_16x16x32_f16(a[m], b[f], acc[m][f], 0, 0, 0);
    }

    #pragma unroll
    for (int f = 0; f < 3; f++) {
        int col = 48 * w + 16 * f + ln15;
        float bias = (col < 64) ? bq[col] : (col < 128) ? bk[col - 64] : bv[col - 128];
        #pragma unroll
        for (int m = 0; m < 2; m++) {
            #pragma unroll
            for (int i = 0; i < 4; i++) {
                int t = r0 + 16 * m + (lane >> 4) * 4 + i;
                int bb = t >> 12;
                int tt = t & (SEQ - 1);
                float v = acc[m][f][i] + bias;
                if (col < 64)
                    Q[((size_t)bb * SEQ + tt) * HDIM + col] = (h16)(v * 0.125f);
                else if (col < 128)
                    K[((size_t)bb * SEQ + tt) * HDIM + (col - 64)] = (h16)v;
                else {
                    int tp = (tt & ~15) | kperm(tt & 15);
                    Vt[((size_t)bb * HDIM + (col - 128)) * SEQ + tp] = (h16)v;
                }
            }
        }
    }
}

// ---------------- flash compute step: QK MFMA -> online softmax -> PV MFMA ----------------
__device__ __forceinline__ void flash_compute(
    h16x8 K0, h16x8 K1, h16x8 K2, h16x8 K3,
    h16x8 V0, h16x8 V1, h16x8 V2, h16x8 V3,
    h16x8 q0v, h16x8 q1v, h16x8 q2v, h16x8 q3v,
    int kt0, int q0, int qg, int hi,
    f32x16& o0, f32x16& o1, float& m_i, float& l_i)
{
    f32x16 s = {};
    __builtin_amdgcn_s_setprio(1);
    s = __builtin_amdgcn_mfma_f32_32x32x16_f16(K0, q0v, s, 0, 0, 0);
    s = __builtin_amdgcn_mfma_f32_32x32x16_f16(K1, q1v, s, 0, 0, 0);
    s = __builtin_amdgcn_mfma_f32_32x32x16_f16(K2, q2v, s, 0, 0, 0);
    s = __builtin_amdgcn_mfma_f32_32x32x16_f16(K3, q3v, s, 0, 0, 0);
    __builtin_amdgcn_s_setprio(0);

    float sc[16];
    #pragma unroll
    for (int r = 0; r < 16; r++) sc[r] = s[r];
    if (kt0 + 31 > q0) {  // tile may contain masked entries (wave-uniform test)
        #pragma unroll
        for (int r = 0; r < 16; r++) {
            int kg = kt0 + (r & 3) + 8 * (r >> 2) + 4 * hi;
            if (kg > qg) sc[r] = -1e30f;
        }
    }
    float tm = sc[0];
    #pragma unroll
    for (int r = 1; r < 16; r++) tm = fmaxf(tm, sc[r]);
    tm = fmaxf(tm, __shfl_xor(tm, 32));
    float mn = fmaxf(m_i, tm);
    float al = __expf(m_i - mn);
    m_i = mn;
    float p[16], rs = 0.f;
    #pragma unroll
    for (int r = 0; r < 16; r++) { p[r] = __expf(sc[r] - mn); rs += p[r]; }
    rs += __shfl_xor(rs, 32);
    l_i = l_i * al + rs;
    #pragma unroll
    for (int r = 0; r < 16; r++) { o0[r] *= al; o1[r] *= al; }

    h16x8 pb0, pb1;
    #pragma unroll
    for (int j = 0; j < 8; j++) { pb0[j] = (h16)p[j]; pb1[j] = (h16)p[8 + j]; }

    __builtin_amdgcn_s_setprio(1);
    o0 = __builtin_amdgcn_mfma_f32_32x32x16_f16(V0, pb0, o0, 0, 0, 0);
    o0 = __builtin_amdgcn_mfma_f32_32x32x16_f16(V1, pb1, o0, 0, 0, 0);
    o1 = __builtin_amdgcn_mfma_f32_32x32x16_f16(V2, pb0, o1, 0, 0, 0);
    o1 = __builtin_amdgcn_mfma_f32_32x32x16_f16(V3, pb1, o1, 0, 0, 0);
    __builtin_amdgcn_s_setprio(0);
}

// issue the 8 loads for one 32-wide KV tile into named buffer set B (A or B)
#define ISSUE(B, KT) {                                                        \
    const h16* kp_ = krow + (size_t)(KT) * HDIM;                              \
    gload(k##B##0, kp_);      gload(k##B##1, kp_ + 16);                       \
    gload(k##B##2, kp_ + 32); gload(k##B##3, kp_ + 48);                       \
    gload(v##B##0, vrow0 + (KT));      gload(v##B##1, vrow0 + (KT) + 16);     \
    gload(v##B##2, vrow1 + (KT));      gload(v##B##3, vrow1 + (KT) + 16); }

#define COMPUTE(B, T) flash_compute(                                          \
    k##B##0, k##B##1, k##B##2, k##B##3, v##B##0, v##B##1, v##B##2, v##B##3,   \
    qb0, qb1, qb2, qb3, S + 32 * (T), q0, qg, hi, o0, o1, m_i, l_i);

#define STEP(CUR, NXT, T) {                                                   \
    ISSUE(NXT, S + 32 * ((T) + 1))                                            \
    asm volatile("s_waitcnt vmcnt(8)" ::: "memory");                          \
    __builtin_amdgcn_sched_barrier(0);                                        \
    COMPUTE(CUR, T) }

#define STEP_LAST(CUR, T) {                                                   \
    asm volatile("s_waitcnt vmcnt(0)" ::: "memory");                          \
    __builtin_amdgcn_sched_barrier(0);                                        \
    COMPUTE(CUR, T) }

// ---------------- causal flash attention partial: all-register, asm-pipelined ----------------
// Wave owns (batch, 32 q-rows, 256 kv). Swapped QK -> q on output column (lane&31).
// PV: V as A operand (pre-permuted Vt), P as B operand. K/V double-buffered in NAMED
// registers via inline-asm loads + counted vmcnt(8) -- compiler cannot defeat the pipeline.
__global__ __launch_bounds__(256, 2) void flash(
    const h16* __restrict__ Q, const h16* __restrict__ K, const h16* __restrict__ Vt,
    h16* __restrict__ o_part, float* __restrict__ ml_part)
{
    int wid = threadIdx.x >> 6;
    int lane = threadIdx.x & 63;
    int bid = blockIdx.x;                  // grid = BATCH*NQT*4
    int quarter = bid & 3;
    int rest = bid >> 2;
    int qtidx = rest & (NQT - 1);
    int batch = rest >> 7;
    int qt = NQT - 1 - qtidx;              // longest q-tiles first
    int c = quarter * 4 + wid;
    int nc = (qt >> 3) + 1;
    if (c >= nc) return;

    int q0 = qt * QBLK;
    int S = c * CHUNK;
    int l31 = lane & 31;
    int hi = lane >> 5;
    int qg = q0 + l31;

    const h16* Qb = Q + (size_t)batch * SEQ * HDIM;
    const h16* Kb = K + (size_t)batch * SEQ * HDIM;
    const h16* Vb = Vt + (size_t)batch * HDIM * SEQ;
    const h16* krow = Kb + (size_t)l31 * HDIM + 8 * hi;
    const h16* vrow0 = Vb + (size_t)l31 * SEQ + 8 * hi;
    const h16* vrow1 = Vb + (size_t)(32 + l31) * SEQ + 8 * hi;

    // Q fragment loads (also asm, so the compiler tracks no VMEM of its own in the loop)
    h16x8 qb0, qb1, qb2, qb3;
    {
        const h16* qp = Qb + (size_t)(q0 + l31) * HDIM + 8 * hi;
        gload(qb0, qp); gload(qb1, qp + 16); gload(qb2, qp + 32); gload(qb3, qp + 48);
    }

    h16x8 kA0, kA1, kA2, kA3, vA0, vA1, vA2, vA3;
    h16x8 kB0, kB1, kB2, kB3, vB0, vB1, vB2, vB3;

    f32x16 o0 = {}, o1 = {};
    float m_i = -1e30f, l_i = 0.f;

    ISSUE(A, S)            // prologue: tile 0 in flight (12 outstanding incl. qb)

    STEP(A, B, 0)          // issue tile1 -> 20 outstanding; vmcnt(8) = qb+tile0 done
    STEP(B, A, 1)
    STEP(A, B, 2)
    STEP(B, A, 3)
    STEP(A, B, 4)
    STEP(B, A, 5)
    STEP(A, B, 6)
    STEP_LAST(B, 7)

    // write l-normalized partial (f16, 4-wide packed stores) + (m, l) f32
    float inv = 1.f / l_i;
    size_t slot = (size_t)batch * BSLOT + slot_base(qt) + c;
    h16* op = o_part + slot * (QBLK * 64) + l31 * 64;
    #pragma unroll
    for (int q = 0; q < 4; q++) {
        h16x4 pk0, pk1;
        #pragma unroll
        for (int i = 0; i < 4; i++) {
            pk0[i] = (h16)(o0[4 * q + i] * inv);
            pk1[i] = (h16)(o1[4 * q + i] * inv);
        }
        *(h16x4*)(op + 8 * q + 4 * hi) = pk0;
        *(h16x4*)(op + 32 + 8 * q + 4 * hi) = pk1;
    }
    if (hi == 0) {
        ml_part[slot * 64 + l31 * 2] = m_i;
        ml_part[slot * 64 + l31 * 2 + 1] = l_i;
    }
}

// ---------------- combine partials: one block per (batch, qt, row-half) ----------------
__global__ __launch_bounds__(256) void combine(
    const h16* __restrict__ o_part, const float* __restrict__ ml_part,
    float* __restrict__ out)
{
    int bid = blockIdx.x;           // BATCH*NQT*2
    int rh = bid & 1;
    int tile = bid >> 1;
    int batch = tile >> 7;
    int qt = tile & (NQT - 1);
    int q0 = qt * QBLK;
    int nc = (qt >> 3) + 1;
    int col = threadIdx.x & 63;
    int rg = threadIdx.x >> 6;      // 0..3
    size_t base = (size_t)batch * BSLOT + slot_base(qt);

    #pragma unroll
    for (int j = 0; j < 4; j++) {
        int r = rh * 16 + rg * 4 + j;
        float M = -1e30f;
        for (int c = 0; c < nc; c++)
            M = fmaxf(M, ml_part[(base + c) * 64 + r * 2]);
        float L = 0.f, acc = 0.f;
        for (int c = 0; c < nc; c++) {
            float mc = ml_part[(base + c) * 64 + r * 2];
            float lc = ml_part[(base + c) * 64 + r * 2 + 1];
            float wgt = __expf(mc - M) * lc;
            L += wgt;
            acc += wgt * (float)o_part[(base + c) * (QBLK * 64) + r * 64 + col];
        }
        out[((size_t)batch * SEQ + q0 + r) * HDIM + col] = acc / L;
    }
}

extern "C" void kernel_launch(void* const* d_in, const int* in_sizes, int n_in,
                              void* d_out, int out_size, void* d_ws, size_t ws_size,
                              hipStream_t stream) {
    const float* x  = (const float*)d_in[0];
    const float* Wq = (const float*)d_in[1];
    const float* bq = (const float*)d_in[2];
    const float* Wk = (const float*)d_in[3];
    const float* bk = (const float*)d_in[4];
    const float* Wv = (const float*)d_in[5];
    const float* bv = (const float*)d_in[6];
    float* out = (float*)d_out;

    h16* Wt = (h16*)d_ws;
    h16* Q  = Wt + WT_ELEMS;
    h16* K  = Q + QK_ELEMS;
    h16* Vt = K + QK_ELEMS;
    h16* xh = Vt + QK_ELEMS;             // 32 MB, dead after qkv_proj
    h16* o_part = xh;                    // aliases xh (flash phase)
    float* ml_part = (float*)(o_part + (size_t)NSLOT * QBLK * 64);
    // peak ws use ~= 38.4 MiB (< R3-proven 41.3e6 B)

    hipLaunchKernelGGL(prep, dim3(192 + 2048), dim3(256), 0, stream, Wq, Wk, Wv, x, Wt, xh);
    hipLaunchKernelGGL(qkv_proj, dim3(512), dim3(256), 0, stream,
                       xh, Wt, bq, bk, bv, Q, K, Vt);
    hipLaunchKernelGGL(flash, dim3(BATCH * NQT * 4), dim3(256), 0, stream,
                       Q, K, Vt, o_part, ml_part);
    hipLaunchKernelGGL(combine, dim3(BATCH * NQT * 2), dim3(256), 0, stream,
                       o_part, ml_part, out);
}

// Round 9
// 153.282 us; speedup vs baseline: 1.8604x; 1.0308x over previous
//
#include <hip/hip_runtime.h>

#define BATCH 4
#define SEQ 4096
#define DMODEL 1024
#define HDIM 64

#define QBLK 64      // q rows per wave (2 groups of 32)
#define NQT 64       // 64-row q-tiles per batch
#define CHUNK 256    // KV positions per wave
#define ITERS 8      // CHUNK / 32
#define BSLOT 544    // per-batch valid (qt,chunk) slots = sum_qt (qt/4 + 1)

typedef _Float16 h16;
typedef _Float16 h16x8 __attribute__((ext_vector_type(8)));
typedef _Float16 h16x4 __attribute__((ext_vector_type(4)));
typedef float f32x4 __attribute__((ext_vector_type(4)));
typedef float f32x16 __attribute__((ext_vector_type(16)));

#define WT_ELEMS (192 * DMODEL)
#define QK_ELEMS (BATCH * SEQ * HDIM)       // 1048576
#define NSLOT (BATCH * BSLOT)

// valid-slot prefix: qt = 4a+b -> sum_{q<qt} (q/4+1) = (a+1)(2a+b)
__device__ __forceinline__ int slot_base(int qt) {
    int a = qt >> 2, b = qt & 3;
    return (a + 1) * (2 * a + b);
}

// k-slot permutation for MFMA A/B fragments: swap bits 2<->3 (self-inverse)
__device__ __forceinline__ int kperm(int u) {
    return (u & 3) | (((u >> 2) & 1) << 3) | (((u >> 3) & 1) << 2);
}

// compiler-proof async load: issue global_load_dwordx4, completion via explicit vmcnt
__device__ __forceinline__ void gload(h16x8& dst, const h16* p) {
    asm volatile("global_load_dwordx4 %0, %1, off" : "=v"(dst) : "v"(p));
}

// ---------------- prep: Wt transpose + fp16 convert ----------------
__global__ __launch_bounds__(256) void prep(const float* __restrict__ Wq,
                                            const float* __restrict__ Wk,
                                            const float* __restrict__ Wv,
                                            h16* __restrict__ Wt) {
    int b = blockIdx.x;  // 0..191
    const float* W = (b < 64) ? Wq : (b < 128) ? Wk : Wv;
    int c = b & 63;
    for (int k = threadIdx.x; k < DMODEL; k += 256)
        Wt[b * DMODEL + k] = (h16)W[k * HDIM + c];
}

// ---------------- QKV projection GEMM: M=16384, K=1024, N=192, fused fp32->f16 ----------------
// grid 512 (32-row tiles); 4 waves: wave w -> 48 N-cols. 2 M-frags x 3 N-frags.
// Q pre-scaled by 1/8; V stored transposed [B][H][T] with kperm within 16-groups.
__global__ __launch_bounds__(256) void qkv_proj(
    const float* __restrict__ x, const h16* __restrict__ Wt,
    const float* __restrict__ bq, const float* __restrict__ bk, const float* __restrict__ bv,
    h16* __restrict__ Q, h16* __restrict__ K, h16* __restrict__ Vt)
{
    int lane = threadIdx.x & 63;
    int w = threadIdx.x >> 6;
    int r0 = blockIdx.x * 32;
    int ln15 = lane & 15;
    int kc = (lane >> 4) * 8;

    f32x4 acc[2][3];
    #pragma unroll
    for (int m = 0; m < 2; m++)
        #pragma unroll
        for (int f = 0; f < 3; f++) acc[m][f] = 0.f;

    #pragma unroll 4
    for (int k0 = 0; k0 < DMODEL; k0 += 32) {
        h16x8 a[2], b[3];
        #pragma unroll
        for (int m = 0; m < 2; m++) {
            const float* xp = x + (size_t)(r0 + 16 * m + ln15) * DMODEL + k0 + kc;
            f32x4 lo = *(const f32x4*)xp;
            f32x4 hi = *(const f32x4*)(xp + 4);
            h16x8 av;
            #pragma unroll
            for (int j = 0; j < 4; j++) { av[j] = (h16)lo[j]; av[j + 4] = (h16)hi[j]; }
            a[m] = av;
        }
        #pragma unroll
        for (int f = 0; f < 3; f++) {
            int col = 48 * w + 16 * f + ln15;
            b[f] = *(const h16x8*)(Wt + (size_t)col * DMODEL + k0 + kc);
        }
        #pragma unroll
        for (int m = 0; m < 2; m++)
            #pragma unroll
            for (int f = 0; f < 3; f++)
                acc[m][f] = __builtin_amdgcn_mfma_f32_16x16x32_f16(a[m], b[f], acc[m][f], 0, 0, 0);
    }

    #pragma unroll
    for (int f = 0; f < 3; f++) {
        int col = 48 * w + 16 * f + ln15;
        float bias = (col < 64) ? bq[col] : (col < 128) ? bk[col - 64] : bv[col - 128];
        #pragma unroll
        for (int m = 0; m < 2; m++) {
            #pragma unroll
            for (int i = 0; i < 4; i++) {
                int t = r0 + 16 * m + (lane >> 4) * 4 + i;
                int bb = t >> 12;
                int tt = t & (SEQ - 1);
                float v = acc[m][f][i] + bias;
                if (col < 64)
                    Q[((size_t)bb * SEQ + tt) * HDIM + col] = (h16)(v * 0.125f);
                else if (col < 128)
                    K[((size_t)bb * SEQ + tt) * HDIM + (col - 64)] = (h16)v;
                else {
                    int tp = (tt & ~15) | kperm(tt & 15);
                    Vt[((size_t)bb * HDIM + (col - 128)) * SEQ + tp] = (h16)v;
                }
            }
        }
    }
}

// ---------------- flash compute step (one 32-row q-group): QK -> softmax -> PV ----------------
__device__ __forceinline__ void flash_compute(
    h16x8 K0, h16x8 K1, h16x8 K2, h16x8 K3,
    h16x8 V0, h16x8 V1, h16x8 V2, h16x8 V3,
    h16x8 q0v, h16x8 q1v, h16x8 q2v, h16x8 q3v,
    int kt0, int q0g, int qg, int hi,
    f32x16& o0, f32x16& o1, float& m_i, float& l_i)
{
    f32x16 s = {};
    __builtin_amdgcn_s_setprio(1);
    s = __builtin_amdgcn_mfma_f32_32x32x16_f16(K0, q0v, s, 0, 0, 0);
    s = __builtin_amdgcn_mfma_f32_32x32x16_f16(K1, q1v, s, 0, 0, 0);
    s = __builtin_amdgcn_mfma_f32_32x32x16_f16(K2, q2v, s, 0, 0, 0);
    s = __builtin_amdgcn_mfma_f32_32x32x16_f16(K3, q3v, s, 0, 0, 0);
    __builtin_amdgcn_s_setprio(0);

    float sc[16];
    #pragma unroll
    for (int r = 0; r < 16; r++) sc[r] = s[r];
    if (kt0 + 31 > q0g) {  // tile may contain masked entries for this group (uniform test)
        #pragma unroll
        for (int r = 0; r < 16; r++) {
            int kg = kt0 + (r & 3) + 8 * (r >> 2) + 4 * hi;
            if (kg > qg) sc[r] = -1e30f;
        }
    }
    float tm = sc[0];
    #pragma unroll
    for (int r = 1; r < 16; r++) tm = fmaxf(tm, sc[r]);
    tm = fmaxf(tm, __shfl_xor(tm, 32));
    float mn = fmaxf(m_i, tm);
    float al = __expf(m_i - mn);
    m_i = mn;
    float p[16], rs = 0.f;
    #pragma unroll
    for (int r = 0; r < 16; r++) { p[r] = __expf(sc[r] - mn); rs += p[r]; }
    rs += __shfl_xor(rs, 32);
    l_i = l_i * al + rs;
    #pragma unroll
    for (int r = 0; r < 16; r++) { o0[r] *= al; o1[r] *= al; }

    h16x8 pb0, pb1;
    #pragma unroll
    for (int j = 0; j < 8; j++) { pb0[j] = (h16)p[j]; pb1[j] = (h16)p[8 + j]; }

    __builtin_amdgcn_s_setprio(1);
    o0 = __builtin_amdgcn_mfma_f32_32x32x16_f16(V0, pb0, o0, 0, 0, 0);
    o0 = __builtin_amdgcn_mfma_f32_32x32x16_f16(V1, pb1, o0, 0, 0, 0);
    o1 = __builtin_amdgcn_mfma_f32_32x32x16_f16(V2, pb0, o1, 0, 0, 0);
    o1 = __builtin_amdgcn_mfma_f32_32x32x16_f16(V3, pb1, o1, 0, 0, 0);
    __builtin_amdgcn_s_setprio(0);
}

// issue the 8 loads for one 32-wide KV tile into named buffer set B (A or B)
#define ISSUE(B, KT) {                                                        \
    const h16* kp_ = krow + (size_t)(KT) * HDIM;                              \
    gload(k##B##0, kp_);      gload(k##B##1, kp_ + 16);                       \
    gload(k##B##2, kp_ + 32); gload(k##B##3, kp_ + 48);                       \
    gload(v##B##0, vrow0 + (KT));      gload(v##B##1, vrow0 + (KT) + 16);     \
    gload(v##B##2, vrow1 + (KT));      gload(v##B##3, vrow1 + (KT) + 16); }

// both q-groups consume the same K/V tile
#define COMPUTE(B, T) {                                                       \
    flash_compute(k##B##0, k##B##1, k##B##2, k##B##3,                         \
                  v##B##0, v##B##1, v##B##2, v##B##3,                         \
                  qa0, qa1, qa2, qa3, S + 32 * (T), q0, qg0, hi,              \
                  o00, o01, m0, l0);                                          \
    flash_compute(k##B##0, k##B##1, k##B##2, k##B##3,                         \
                  v##B##0, v##B##1, v##B##2, v##B##3,                         \
                  qc0, qc1, qc2, qc3, S + 32 * (T), q0 + 32, qg1, hi,         \
                  o10, o11, m1, l1); }

#define STEP(CUR, NXT, T) {                                                   \
    ISSUE(NXT, S + 32 * ((T) + 1))                                            \
    asm volatile("s_waitcnt vmcnt(8)" ::: "memory");                          \
    __builtin_amdgcn_sched_barrier(0);                                        \
    COMPUTE(CUR, T) }

#define STEP_LAST(CUR, T) {                                                   \
    asm volatile("s_waitcnt vmcnt(0)" ::: "memory");                          \
    __builtin_amdgcn_sched_barrier(0);                                        \
    COMPUTE(CUR, T) }

// ---------------- causal flash attention partial: 64 q-rows/wave, asm-pipelined ----------------
// Wave owns (batch, 64 q-rows, 256 kv): 2 q-groups of 32 share every K/V load (traffic /2).
__global__ __launch_bounds__(256, 2) void flash(
    const h16* __restrict__ Q, const h16* __restrict__ K, const h16* __restrict__ Vt,
    h16* __restrict__ o_part, float* __restrict__ ml_part)
{
    int wid = threadIdx.x >> 6;
    int lane = threadIdx.x & 63;
    int bid = blockIdx.x;                  // grid = BATCH*NQT*5
    int quarter = bid % 5;
    int rest = bid / 5;
    int qtflip = rest & (NQT - 1);
    int batch = rest >> 6;
    int qt = NQT - 1 - qtflip;             // longest q-tiles first
    int c = quarter * 4 + wid;
    int nc = (qt >> 2) + 1;
    if (c >= nc) return;

    int q0 = qt * QBLK;
    int S = c * CHUNK;
    int l31 = lane & 31;
    int hi = lane >> 5;
    int qg0 = q0 + l31;
    int qg1 = q0 + 32 + l31;

    const h16* Qb = Q + (size_t)batch * SEQ * HDIM;
    const h16* Kb = K + (size_t)batch * SEQ * HDIM;
    const h16* Vb = Vt + (size_t)batch * HDIM * SEQ;
    const h16* krow = Kb + (size_t)l31 * HDIM + 8 * hi;
    const h16* vrow0 = Vb + (size_t)l31 * SEQ + 8 * hi;
    const h16* vrow1 = Vb + (size_t)(32 + l31) * SEQ + 8 * hi;

    // Q fragments for both groups (asm loads; drained by first STEP's vmcnt(8))
    h16x8 qa0, qa1, qa2, qa3, qc0, qc1, qc2, qc3;
    {
        const h16* qp = Qb + (size_t)(q0 + l31) * HDIM + 8 * hi;
        gload(qa0, qp); gload(qa1, qp + 16); gload(qa2, qp + 32); gload(qa3, qp + 48);
        const h16* qp2 = qp + 32 * HDIM;
        gload(qc0, qp2); gload(qc1, qp2 + 16); gload(qc2, qp2 + 32); gload(qc3, qp2 + 48);
    }

    h16x8 kA0, kA1, kA2, kA3, vA0, vA1, vA2, vA3;
    h16x8 kB0, kB1, kB2, kB3, vB0, vB1, vB2, vB3;

    f32x16 o00 = {}, o01 = {}, o10 = {}, o11 = {};
    float m0 = -1e30f, l0 = 0.f, m1 = -1e30f, l1 = 0.f;

    ISSUE(A, S)            // prologue: 8 qb + 8 tile0 in flight

    STEP(A, B, 0)          // issue tile1 -> 24 out; vmcnt(8) = qb+tile0 done
    STEP(B, A, 1)
    STEP(A, B, 2)
    STEP(B, A, 3)
    STEP(A, B, 4)
    STEP(B, A, 5)
    STEP(A, B, 6)
    STEP_LAST(B, 7)

    // write l-normalized partials (f16) + (m, l) f32 for both groups
    size_t slot = (size_t)batch * BSLOT + slot_base(qt) + c;
    h16* opb = o_part + slot * (QBLK * 64);
    {
        float inv = 1.f / l0;
        h16* op = opb + l31 * 64;
        #pragma unroll
        for (int q = 0; q < 4; q++) {
            h16x4 pk0, pk1;
            #pragma unroll
            for (int i = 0; i < 4; i++) {
                pk0[i] = (h16)(o00[4 * q + i] * inv);
                pk1[i] = (h16)(o01[4 * q + i] * inv);
            }
            *(h16x4*)(op + 8 * q + 4 * hi) = pk0;
            *(h16x4*)(op + 32 + 8 * q + 4 * hi) = pk1;
        }
    }
    {
        float inv = 1.f / l1;
        h16* op = opb + (32 + l31) * 64;
        #pragma unroll
        for (int q = 0; q < 4; q++) {
            h16x4 pk0, pk1;
            #pragma unroll
            for (int i = 0; i < 4; i++) {
                pk0[i] = (h16)(o10[4 * q + i] * inv);
                pk1[i] = (h16)(o11[4 * q + i] * inv);
            }
            *(h16x4*)(op + 8 * q + 4 * hi) = pk0;
            *(h16x4*)(op + 32 + 8 * q + 4 * hi) = pk1;
        }
    }
    if (hi == 0) {
        ml_part[slot * 128 + l31 * 2] = m0;
        ml_part[slot * 128 + l31 * 2 + 1] = l0;
        ml_part[slot * 128 + (32 + l31) * 2] = m1;
        ml_part[slot * 128 + (32 + l31) * 2 + 1] = l1;
    }
}

// ---------------- combine partials: one block per (batch, qt, row-half of 32) ----------------
__global__ __launch_bounds__(256) void combine(
    const h16* __restrict__ o_part, const float* __restrict__ ml_part,
    float* __restrict__ out)
{
    int bid = blockIdx.x;           // BATCH*NQT*2
    int rh = bid & 1;
    int tile = bid >> 1;
    int batch = tile >> 6;
    int qt = tile & (NQT - 1);
    int q0 = qt * QBLK;
    int nc = (qt >> 2) + 1;
    int col = threadIdx.x & 63;
    int rg = threadIdx.x >> 6;      // 0..3
    size_t base = (size_t)batch * BSLOT + slot_base(qt);

    #pragma unroll
    for (int j = 0; j < 8; j++) {
        int r = rh * 32 + rg * 8 + j;
        float M = -1e30f;
        for (int c = 0; c < nc; c++)
            M = fmaxf(M, ml_part[(base + c) * 128 + r * 2]);
        float L = 0.f, acc = 0.f;
        for (int c = 0; c < nc; c++) {
            float mc = ml_part[(base + c) * 128 + r * 2];
            float lc = ml_part[(base + c) * 128 + r * 2 + 1];
            float wgt = __expf(mc - M) * lc;
            L += wgt;
            acc += wgt * (float)o_part[(base + c) * (QBLK * 64) + r * 64 + col];
        }
        out[((size_t)batch * SEQ + q0 + r) * HDIM + col] = acc / L;
    }
}

extern "C" void kernel_launch(void* const* d_in, const int* in_sizes, int n_in,
                              void* d_out, int out_size, void* d_ws, size_t ws_size,
                              hipStream_t stream) {
    const float* x  = (const float*)d_in[0];
    const float* Wq = (const float*)d_in[1];
    const float* bq = (const float*)d_in[2];
    const float* Wk = (const float*)d_in[3];
    const float* bk = (const float*)d_in[4];
    const float* Wv = (const float*)d_in[5];
    const float* bv = (const float*)d_in[6];
    float* out = (float*)d_out;

    h16* Wt = (h16*)d_ws;
    h16* Q  = Wt + WT_ELEMS;
    h16* K  = Q + QK_ELEMS;
    h16* Vt = K + QK_ELEMS;
    h16* o_part = Vt + QK_ELEMS;
    float* ml_part = (float*)(o_part + (size_t)NSLOT * QBLK * 64);
    // peak ws use: 0.4 + 6 + 17.8 + 1.1 MB ~= 25.3 MiB

    hipLaunchKernelGGL(prep, dim3(192), dim3(256), 0, stream, Wq, Wk, Wv, Wt);
    hipLaunchKernelGGL(qkv_proj, dim3(512), dim3(256), 0, stream,
                       x, Wt, bq, bk, bv, Q, K, Vt);
    hipLaunchKernelGGL(flash, dim3(BATCH * NQT * 5), dim3(256), 0, stream,
                       Q, K, Vt, o_part, ml_part);
    hipLaunchKernelGGL(combine, dim3(BATCH * NQT * 2), dim3(256), 0, stream,
                       o_part, ml_part, out);
}